// Round 1
// baseline (250.148 us; speedup 1.0000x reference)
//
#include <hip/hip_runtime.h>

#define BDIM 32768
#define VDIM 256
#define KVAR 4
#define EDIM 2048
#define SEGS 16
#define SEGLEN 128   // EDIM / SEGS

typedef __attribute__((ext_vector_type(8))) short short8;
typedef __attribute__((ext_vector_type(4))) float f32x4;

__device__ __forceinline__ unsigned short f2b(float f){
  union { float f; unsigned u; } v; v.f = f;
  unsigned r = v.u + 0x7FFFu + ((v.u >> 16) & 1u);   // round-to-nearest-even
  return (unsigned short)(r >> 16);
}
__device__ __forceinline__ float b2f(unsigned short h){
  union { unsigned u; float f; } v; v.u = ((unsigned)h) << 16;
  return v.f;
}
__device__ __forceinline__ short8 ldb8(const unsigned short* p){
  return *(const short8*)p;
}

// ---- MFMA cores ------------------------------------------------------------
// A from XOR-swizzled LDS (element col ^ ((row&7)<<3)); rows rl0, rl0+16
// B from global (L2-resident weight panels), row = output col
// D frag: col = lane&15, row = (lane>>4)*4 + reg   [measured: learn_hip m89]
template<int NF, int KSZ>
__device__ __forceinline__ void mm_l2(const unsigned short* Alds, int ldaE,
                                      const unsigned short* Bt, int ldb,
                                      int rl0, int c0, int kb,
                                      f32x4 (&acc)[2][NF])
{
  int sw = (rl0 & 7) << 3;     // (rl0+16)&7 == rl0&7
#pragma unroll
  for (int k0 = 0; k0 < KSZ; k0 += 32){
    int ka = k0 + kb;
    short8 a0 = *(const short8*)&Alds[(size_t)rl0 * ldaE + (ka ^ sw)];
    short8 a1 = *(const short8*)&Alds[(size_t)(rl0+16) * ldaE + (ka ^ sw)];
#pragma unroll
    for (int fn = 0; fn < NF; fn++){
      short8 b = ldb8(Bt + (size_t)(c0 + fn*16)*ldb + ka);
      acc[0][fn] = __builtin_amdgcn_mfma_f32_16x16x32_bf16(a0, b, acc[0][fn], 0, 0, 0);
      acc[1][fn] = __builtin_amdgcn_mfma_f32_16x16x32_bf16(a1, b, acc[1][fn], 0, 0, 0);
    }
  }
}

// single 16-row A frag version (for the P2 stage)
template<int NF, int KSZ>
__device__ __forceinline__ void mm_l1(const unsigned short* Alds, int ldaE,
                                      const unsigned short* Bt, int ldb,
                                      int rl0, int c0, int kb,
                                      f32x4 (&acc)[NF])
{
  int sw = (rl0 & 7) << 3;
#pragma unroll
  for (int k0 = 0; k0 < KSZ; k0 += 32){
    int ka = k0 + kb;
    short8 a0 = *(const short8*)&Alds[(size_t)rl0 * ldaE + (ka ^ sw)];
#pragma unroll
    for (int fn = 0; fn < NF; fn++){
      short8 b = ldb8(Bt + (size_t)(c0 + fn*16)*ldb + ka);
      acc[fn] = __builtin_amdgcn_mfma_f32_16x16x32_bf16(a0, b, acc[fn], 0, 0, 0);
    }
  }
}

// ---- merged prep + seg_build (block-partitioned) ---------------------------
__global__ __launch_bounds__(256) void prep_seg(
    const float* X, const float* IV, const int* ivars,
    const float* eW1, const float* eW2, const float* pW1, const float* pW2,
    const int* cidx, const int* eidx, const float* stren,
    unsigned short* XB,
    unsigned short* bt1, unsigned short* bt2,
    unsigned short* w1ab, unsigned short* w1c,
    unsigned short* w2bf, float* w1bcol, int* colmap,
    float* delta, float* segs)
{
  if (blockIdx.x < 1024){
    // ---- seg_build: P_s = prod of T_k; wave per (seg,row-quad)
    __shared__ int lc[SEGLEN];
    __shared__ int le[SEGLEN];
    __shared__ float la[SEGLEN];
    int bid = blockIdx.x;            // 64 per segment, 4 rows each
    int seg = bid >> 6;
    int rowbase = (bid & 63) * 4;
    int w = threadIdx.x >> 6, lane = threadIdx.x & 63;
    int row = rowbase + w;
    int k0 = seg * SEGLEN;
    for (int t = threadIdx.x; t < SEGLEN; t += 256){
      lc[t] = cidx[k0 + t]; le[t] = eidx[k0 + t]; la[t] = stren[k0 + t] * 0.1f;
    }
    __syncthreads();
    float r0 = (row == lane)        ? 1.f : 0.f;
    float r1 = (row == lane + 64)   ? 1.f : 0.f;
    float r2 = (row == lane + 128)  ? 1.f : 0.f;
    float r3 = (row == lane + 192)  ? 1.f : 0.f;
    for (int t = 0; t < SEGLEN; t++){
      int cs = __builtin_amdgcn_readfirstlane(lc[t]);
      int es = __builtin_amdgcn_readfirstlane(le[t]);
      float a = la[t];
      float vr;
      switch (cs >> 6){ case 0: vr = r0; break; case 1: vr = r1; break;
                        case 2: vr = r2; break; default: vr = r3; }
      float v = __shfl(vr, cs & 63, 64);
      float add = (lane == (es & 63)) ? a * v : 0.f;
      switch (es >> 6){ case 0: r0 += add; break; case 1: r1 += add; break;
                        case 2: r2 += add; break; default: r3 += add; }
    }
    float* out = segs + (size_t)seg * 65536 + (size_t)row * 256;
    out[lane] = r0; out[lane + 64] = r1; out[lane + 128] = r2; out[lane + 192] = r3;
    return;
  }
  // ---- prep: grid-stride over blocks 1024..2047
  int stride = 1024 * 256;
  int g0 = (blockIdx.x - 1024) * 256 + threadIdx.x;
  for (int i = g0; i < (BDIM * VDIM) / 8; i += stride){
    const float* p = X + (size_t)i * 8;
    f32x4 lo = *(const f32x4*)p;
    f32x4 hi = *(const f32x4*)(p + 4);
    short8 r;
    r[0]=(short)f2b(lo[0]); r[1]=(short)f2b(lo[1]); r[2]=(short)f2b(lo[2]); r[3]=(short)f2b(lo[3]);
    r[4]=(short)f2b(hi[0]); r[5]=(short)f2b(hi[1]); r[6]=(short)f2b(hi[2]); r[7]=(short)f2b(hi[3]);
    *(short8*)(XB + (size_t)i * 8) = r;
  }
  for (int i = g0; i < 65536; i += stride) bt1[i] = f2b(eW1[i]);
  for (int i = g0; i < 65536; i += stride){
    int v = i >> 8, r = i & 255;
    bt2[i] = f2b(eW2[(r >> 6) * 16384 + v * 64 + (r & 63)]);
  }
  for (int i = g0; i < 32768; i += stride){
    int o = i >> 8, v = i & 255;
    w1ab[i] = f2b(pW1[o*768 + v] + pW1[o*768 + 256 + v]);
    w1c[i]  = f2b(pW1[o*768 + 512 + v]);
  }
  for (int i = g0; i < 8192; i += stride) w2bf[i] = f2b(pW2[i]);
  for (int i = g0; i < 512; i += stride){
    int o = i >> 2, k = i & 3;
    w1bcol[i] = pW1[o*768 + 256 + ivars[k]];
  }
  for (int i = g0; i < VDIM; i += stride){
    int m = -1;
#pragma unroll
    for (int k = 0; k < KVAR; k++) if (ivars[k] == i) m = k;
    colmap[i] = m;
  }
  for (int i = g0; i < BDIM * KVAR; i += stride){
    int b = i >> 2, k = i & 3;
    delta[i] = IV[i] - X[(size_t)b * VDIM + ivars[k]];
  }
}

// ---- combine: Out[m] = S[4m]*S[4m+1]*S[4m+2]*S[4m+3], 4 rows per block -----
__global__ __launch_bounds__(256) void combine4(const float* S, float* Out)
{
  int m = blockIdx.x >> 6;
  int rb = (blockIdx.x & 63) * 4;
  int c = threadIdx.x;
  __shared__ float v[4][256];
  const float* base = S + (size_t)m * 4 * 65536;
#pragma unroll
  for (int r = 0; r < 4; r++) v[r][c] = base[(size_t)(rb + r) * 256 + c];
  __syncthreads();
  for (int p = 1; p < 4; p++){
    const float* Bm = base + (size_t)p * 65536;
    float a0 = 0.f, a1 = 0.f, a2 = 0.f, a3 = 0.f;
    for (int k = 0; k < 256; k += 4){
      f32x4 v0 = *(const f32x4*)&v[0][k];
      f32x4 v1 = *(const f32x4*)&v[1][k];
      f32x4 v2 = *(const f32x4*)&v[2][k];
      f32x4 v3 = *(const f32x4*)&v[3][k];
#pragma unroll
      for (int j = 0; j < 4; j++){
        float bk = Bm[(size_t)(k + j) * 256 + c];
        a0 += v0[j] * bk; a1 += v1[j] * bk; a2 += v2[j] * bk; a3 += v3[j] * bk;
      }
    }
    __syncthreads();
    v[0][c] = a0; v[1][c] = a1; v[2][c] = a2; v[3][c] = a3;
    __syncthreads();
  }
#pragma unroll
  for (int r = 0; r < 4; r++) Out[(size_t)m * 65536 + (size_t)(rb + r) * 256 + c] = v[r][c];
}

// ---- M = R*R*R, written transposed bf16: Mt[c][r] --------------------------
__global__ __launch_bounds__(256) void powM(const float* R, unsigned short* Mt)
{
  int rb = blockIdx.x * 4;
  int c = threadIdx.x;
  __shared__ float v[4][256];
#pragma unroll
  for (int r = 0; r < 4; r++) v[r][c] = R[(size_t)(rb + r) * 256 + c];
  __syncthreads();
  for (int p = 0; p < 2; p++){
    float a0 = 0.f, a1 = 0.f, a2 = 0.f, a3 = 0.f;
    for (int k = 0; k < 256; k += 4){
      f32x4 v0 = *(const f32x4*)&v[0][k];
      f32x4 v1 = *(const f32x4*)&v[1][k];
      f32x4 v2 = *(const f32x4*)&v[2][k];
      f32x4 v3 = *(const f32x4*)&v[3][k];
#pragma unroll
      for (int j = 0; j < 4; j++){
        float bk = R[(size_t)(k + j) * 256 + c];
        a0 += v0[j] * bk; a1 += v1[j] * bk; a2 += v2[j] * bk; a3 += v3[j] * bk;
      }
    }
    __syncthreads();
    v[0][c] = a0; v[1][c] = a1; v[2][c] = a2; v[3][c] = a3;
    __syncthreads();
  }
#pragma unroll
  for (int r = 0; r < 4; r++) Mt[(size_t)c * 256 + (rb + r)] = f2b(v[r][c]);
}

// ---- MEGA: H -> eff -> final -> P1 -> P2/plaus + impact --------------------
// 32-row stripe per block, 8 waves (1 rowg x 8 colg), wave tile 32x32.
// Grid = 1024 blocks -> 4 blocks/CU -> 32 waves/CU (occupancy was the cap at
// the previous 512x(64-row) shape: 2 blocks/CU = 45.7%).
// XB tile staged ONCE into LDS (xb) and reused by stages 1,2,3,4 (was 4 HBM
// passes over the full 16MB XB). buf is the stage-to-stage 32x256 scratch.
__global__ __launch_bounds__(512, 8) void mega(
    const float* IV, const unsigned short* XB,
    const unsigned short* Bt1, const unsigned short* Bt2, const unsigned short* Mt,
    const unsigned short* W1ab, const unsigned short* W1c, const unsigned short* W2bf,
    const float* eb1, const float* eb2, const float* delta, const int* colmap,
    const float* w1bcol, const float* pb1, const float* pb2,
    const float* W3, const float* pb3,
    float* effOut, float* outF, float* plausOut, float* impOut)
{
  __shared__ unsigned short xb[32 * 256];    // 16 KB, X tile (swizzled bf16), live all kernel
  __shared__ unsigned short buf[32 * 256];   // 16 KB, reused every stage
  __shared__ float impLds[32 * 8];
  int tid = threadIdx.x, w = tid >> 6, lane = tid & 63;
  int rowBlk = blockIdx.x * 32;
  int rl0 = lane & 15;
  int colBase = w * 32;
  int c0 = colBase + (lane & 15);
  int kb = (lane >> 4) * 8;
  f32x4 acc[2][2];

  // ---- stage 0: XB tile -> LDS (swizzled, same XOR as all LDS A-reads)
  for (int c = tid; c < 1024; c += 512){
    int row = c >> 5, k8 = (c & 31) << 3;
    short8 v = ldb8(XB + (size_t)(rowBlk + row) * 256 + k8);
    *(short8*)&xb[row * 256 + (k8 ^ ((row & 7) << 3))] = v;
  }
  __syncthreads();

  // ---- stage 1: H = relu(X@W1^T + b1) * |delta_k| -> buf (swizzled bf16)
#pragma unroll
  for (int fm = 0; fm < 2; fm++)
#pragma unroll
    for (int fn = 0; fn < 2; fn++) acc[fm][fn] = (f32x4){0.f,0.f,0.f,0.f};
  mm_l2<2, VDIM>(xb, 256, Bt1, VDIM, rl0, c0, kb, acc);
  {
    float b1v[2];
#pragma unroll
    for (int fn = 0; fn < 2; fn++) b1v[fn] = eb1[colBase + fn*16 + (lane & 15)];
    int kI = w >> 1;                       // colg*32 spans: k index = colBase/64
#pragma unroll
    for (int fm = 0; fm < 2; fm++)
#pragma unroll
      for (int i = 0; i < 4; i++){
        int rl = fm*16 + (lane >> 4)*4 + i;
        int gr = rowBlk + rl;
        float mg = fabsf(delta[gr*4 + kI]);
        int sw = (rl & 7) << 3;
#pragma unroll
        for (int fn = 0; fn < 2; fn++){
          int col = colBase + fn*16 + (lane & 15);
          float h = acc[fm][fn][i] + b1v[fn];
          h = h > 0.f ? h : 0.f;
          buf[(size_t)rl*256 + (col ^ sw)] = f2b(h * mg);
        }
      }
  }
  __syncthreads();

  // ---- stage 2: eff = Hs@W2f + sum|d_k| b2[k] ; d0 -> buf
#pragma unroll
  for (int fm = 0; fm < 2; fm++)
#pragma unroll
    for (int fn = 0; fn < 2; fn++) acc[fm][fn] = (f32x4){0.f,0.f,0.f,0.f};
  mm_l2<2, VDIM>(buf, 256, Bt2, VDIM, rl0, c0, kb, acc);
  __syncthreads();                       // all Hs reads done before overwrite
  {
    float bb0[2], bb1[2], bb2[2], bb3[2];
    int imv[2];
#pragma unroll
    for (int fn = 0; fn < 2; fn++){
      int col = colBase + fn*16 + (lane & 15);
      bb0[fn] = eb2[col]; bb1[fn] = eb2[256 + col];
      bb2[fn] = eb2[512 + col]; bb3[fn] = eb2[768 + col];
      imv[fn] = colmap[col];
    }
#pragma unroll
    for (int fm = 0; fm < 2; fm++)
#pragma unroll
      for (int i = 0; i < 4; i++){
        int rl = fm*16 + (lane >> 4)*4 + i;
        int gr = rowBlk + rl;
        f32x4 dl = *(const f32x4*)&delta[gr*4];
        float d0a = fabsf(dl[0]), d1a = fabsf(dl[1]), d2a = fabsf(dl[2]), d3a = fabsf(dl[3]);
        int sw = (rl & 7) << 3;
#pragma unroll
        for (int fn = 0; fn < 2; fn++){
          int col = colBase + fn*16 + (lane & 15);
          float eff = acc[fm][fn][i] + d0a*bb0[fn] + d1a*bb1[fn] + d2a*bb2[fn] + d3a*bb3[fn];
          size_t idx = (size_t)gr*VDIM + col;
          effOut[idx] = eff;
          float base = (imv[fn] >= 0) ? IV[gr*4 + imv[fn]]
                                      : b2f(xb[(size_t)rl*256 + (col ^ sw)]);
          buf[(size_t)rl*256 + (col ^ sw)] = f2b(base + eff);
        }
      }
  }
  __syncthreads();

  // ---- stage 3: final = Ds@M -> outF ; Fin -> buf ; impact partials -> LDS
#pragma unroll
  for (int fm = 0; fm < 2; fm++)
#pragma unroll
    for (int fn = 0; fn < 2; fn++) acc[fm][fn] = (f32x4){0.f,0.f,0.f,0.f};
  mm_l2<2, VDIM>(buf, 256, Mt, VDIM, rl0, c0, kb, acc);
  __syncthreads();                       // all Ds reads done before overwrite
  {
#pragma unroll
    for (int fm = 0; fm < 2; fm++)
#pragma unroll
      for (int i = 0; i < 4; i++){
        int rl = fm*16 + (lane >> 4)*4 + i;
        int gr = rowBlk + rl;
        int sw = (rl & 7) << 3;
        float ss = 0.f;
#pragma unroll
        for (int fn = 0; fn < 2; fn++){
          int col = colBase + fn*16 + (lane & 15);
          size_t idx = (size_t)gr*VDIM + col;
          float fv = acc[fm][fn][i];
          outF[idx] = fv;
          buf[(size_t)rl*256 + (col ^ sw)] = f2b(fv);
          float d = fv - b2f(xb[(size_t)rl*256 + (col ^ sw)]);
          ss += d * d;
        }
        ss += __shfl_xor(ss, 1, 64); ss += __shfl_xor(ss, 2, 64);
        ss += __shfl_xor(ss, 4, 64); ss += __shfl_xor(ss, 8, 64);
        if ((lane & 15) == 0) impLds[rl*8 + w] = ss;
      }
  }
  __syncthreads();

  // ---- stage 4: P1 = relu(X@W1ab^T + Fin@W1c^T + delta corr + b1) -> buf
  {
    f32x4 a4[2][1];
#pragma unroll
    for (int fm = 0; fm < 2; fm++) a4[fm][0] = (f32x4){0.f,0.f,0.f,0.f};
    int c4 = w*16 + (lane & 15);
    mm_l2<1, VDIM>(xb, 256, W1ab, VDIM, rl0, c4, kb, a4);
    mm_l2<1, VDIM>(buf, 256, W1c, VDIM, rl0, c4, kb, a4);
    __syncthreads();                     // all Fin reads done before overwrite
    float bv = pb1[c4];
    f32x4 wb = *(const f32x4*)&w1bcol[c4*4];
#pragma unroll
    for (int fm = 0; fm < 2; fm++)
#pragma unroll
      for (int i = 0; i < 4; i++){
        int rl = fm*16 + (lane >> 4)*4 + i;
        int gr = rowBlk + rl;
        f32x4 dl = *(const f32x4*)&delta[gr*4];
        int sw = (rl & 7) << 3;
        float p = a4[fm][0][i] + bv
                + dl[0]*wb[0] + dl[1]*wb[1] + dl[2]*wb[2] + dl[3]*wb[3];
        p = p > 0.f ? p : 0.f;
        buf[(size_t)rl*128 + (c4 ^ sw)] = f2b(p);
      }
  }
  __syncthreads();

  // ---- stage 5: P2 = relu(P1@W2^T + b2); plaus; impact finish
  if (w < 2){
    int rl0b = w * 16 + (lane & 15);
    f32x4 a2[4];
#pragma unroll
    for (int fn = 0; fn < 4; fn++) a2[fn] = (f32x4){0.f,0.f,0.f,0.f};
    mm_l1<4, 128>(buf, 128, W2bf, 128, rl0b, (lane & 15), kb, a2);
    float b2v[4], w3v[4];
#pragma unroll
    for (int fn = 0; fn < 4; fn++){
      int col = fn*16 + (lane & 15);
      b2v[fn] = pb2[col]; w3v[fn] = W3[col];
    }
    float b3v = pb3[0];
#pragma unroll
    for (int i = 0; i < 4; i++){
      float s = 0.f;
#pragma unroll
      for (int fn = 0; fn < 4; fn++){
        float p2 = a2[fn][i] + b2v[fn];
        p2 = p2 > 0.f ? p2 : 0.f;
        s += p2 * w3v[fn];
      }
      s += __shfl_xor(s, 1, 64); s += __shfl_xor(s, 2, 64);
      s += __shfl_xor(s, 4, 64); s += __shfl_xor(s, 8, 64);
      if ((lane & 15) == 0){
        int gr = rowBlk + w*16 + (lane >> 4)*4 + i;
        plausOut[gr] = 1.f / (1.f + expf(-(s + b3v)));
      }
    }
  } else if (w == 2 && lane < 32){
    f32x4 v0 = *(const f32x4*)&impLds[lane * 8];
    f32x4 v1 = *(const f32x4*)&impLds[lane * 8 + 4];
    impOut[rowBlk + lane] = sqrtf(v0[0]+v0[1]+v0[2]+v0[3]+v1[0]+v1[1]+v1[2]+v1[3]);
  }
}

// ---- workspace layout (bytes) ----------------------------------------------
#define WS_XB     ((size_t)0)           // 16 MB
#define WS_DELTA  ((size_t)16777216)    // 512 KB
#define WS_SEG    ((size_t)17301504)    // 4 MB
#define WS_T2     ((size_t)21495808)    // 1 MB
#define WS_R      ((size_t)22544384)    // 256 KB
#define WS_MT     ((size_t)22806528)    // 128 KB
#define WS_BT1    ((size_t)22937600)    // 128 KB
#define WS_BT2    ((size_t)23068672)    // 128 KB
#define WS_W1AB   ((size_t)23199744)    // 64 KB
#define WS_W1C    ((size_t)23265280)    // 64 KB
#define WS_W2BF   ((size_t)23330816)    // 16 KB
#define WS_W1BCOL ((size_t)23347200)    // 2 KB
#define WS_COLMAP ((size_t)23349248)    // 1 KB

extern "C" void kernel_launch(void* const* d_in, const int* in_sizes, int n_in,
                              void* d_out, int out_size, void* d_ws, size_t ws_size,
                              hipStream_t stream)
{
  const float* X     = (const float*)d_in[0];
  const float* IV    = (const float*)d_in[1];
  const float* STR   = (const float*)d_in[2];
  const int*   IVARS = (const int*)d_in[3];
  const int*   CIDX  = (const int*)d_in[4];
  const int*   EIDX  = (const int*)d_in[5];
  const float* EW1   = (const float*)d_in[6];
  const float* EB1   = (const float*)d_in[7];
  const float* EW2   = (const float*)d_in[8];
  const float* EB2   = (const float*)d_in[9];
  const float* PW1   = (const float*)d_in[10];
  const float* PB1   = (const float*)d_in[11];
  const float* PW2   = (const float*)d_in[12];
  const float* PB2   = (const float*)d_in[13];
  const float* PW3   = (const float*)d_in[14];
  const float* PB3   = (const float*)d_in[15];

  char* ws = (char*)d_ws;
  unsigned short* XB     = (unsigned short*)(ws + WS_XB);
  float*          DELTA  = (float*)(ws + WS_DELTA);
  float*          SEG    = (float*)(ws + WS_SEG);
  float*          T2     = (float*)(ws + WS_T2);
  float*          Rm     = (float*)(ws + WS_R);
  unsigned short* MT     = (unsigned short*)(ws + WS_MT);
  unsigned short* BT1    = (unsigned short*)(ws + WS_BT1);
  unsigned short* BT2    = (unsigned short*)(ws + WS_BT2);
  unsigned short* W1AB   = (unsigned short*)(ws + WS_W1AB);
  unsigned short* W1C    = (unsigned short*)(ws + WS_W1C);
  unsigned short* W2BF   = (unsigned short*)(ws + WS_W2BF);
  float*          W1BCOL = (float*)(ws + WS_W1BCOL);
  int*            COLMAP = (int*)(ws + WS_COLMAP);

  float* outF   = (float*)d_out;                       // final_cf  [B,V]
  float* outEff = outF + (size_t)BDIM * VDIM;          // effects   [B,V]
  float* outPl  = outEff + (size_t)BDIM * VDIM;        // plaus     [B]
  float* outIm  = outPl + BDIM;                        // impact    [B]

  prep_seg<<<2048, 256, 0, stream>>>(X, IV, IVARS, EW1, EW2, PW1, PW2,
                                     CIDX, EIDX, STR,
                                     XB, BT1, BT2, W1AB, W1C, W2BF, W1BCOL, COLMAP,
                                     DELTA, SEG);
  combine4<<<256, 256, 0, stream>>>(SEG, T2);    // 16 segs -> 4
  combine4<<<64, 256, 0, stream>>>(T2, Rm);      // 4 -> R
  powM<<<64, 256, 0, stream>>>(Rm, MT);          // M = R^3, transposed bf16

  mega<<<1024, 512, 0, stream>>>(IV, XB, BT1, BT2, MT, W1AB, W1C, W2BF,
                                 EB1, EB2, DELTA, COLMAP, W1BCOL,
                                 PB1, PB2, PW3, PB3,
                                 outEff, outF, outPl, outIm);

  (void)in_sizes; (void)n_in; (void)out_size; (void)ws_size;
}

// Round 2
// 205.350 us; speedup vs baseline: 1.2182x; 1.2182x over previous
//
#include <hip/hip_runtime.h>

#define BDIM 32768
#define VDIM 256
#define KVAR 4
#define EDIM 2048
#define SEGS 16
#define SEGLEN 128   // EDIM / SEGS

typedef __attribute__((ext_vector_type(8))) short short8;
typedef __attribute__((ext_vector_type(4))) float f32x4;

__device__ __forceinline__ unsigned short f2b(float f){
  union { float f; unsigned u; } v; v.f = f;
  unsigned r = v.u + 0x7FFFu + ((v.u >> 16) & 1u);   // round-to-nearest-even
  return (unsigned short)(r >> 16);
}
__device__ __forceinline__ float b2f(unsigned short h){
  union { unsigned u; float f; } v; v.u = ((unsigned)h) << 16;
  return v.f;
}
__device__ __forceinline__ short8 ldb8(const unsigned short* p){
  return *(const short8*)p;
}

// async 16B global -> LDS (dest = wave-uniform base + lane*16)
__device__ __forceinline__ void gl_lds16(const unsigned short* g, unsigned short* l){
  __builtin_amdgcn_global_load_lds(
      (const __attribute__((address_space(1))) unsigned int*)g,
      (__attribute__((address_space(3))) unsigned int*)l, 16, 0, 0);
}

// ---- B-panel LDS staging ---------------------------------------------------
// Bs layout: panel row r (= output col) -> 64 k-elems (128 B), 16B slot s holds
// global slot (s ^ (r&7))  [source-swizzled so swizzled reads are conflict-free]
// One wave issue = 8 rows (64 lanes x 16B = 1 KB).
__device__ __forceinline__ void stage256(const unsigned short* Bt, int kB,
                                         int w, int lane, unsigned short* Bs){
#pragma unroll
  for (int i = 0; i < 4; i++){
    int g8 = i*8 + w;                  // row-group of 8 (0..31)
    int r  = g8*8 + (lane >> 3);
    int s  = lane & 7;
    gl_lds16(Bt + (size_t)r*VDIM + kB + ((s ^ (r & 7)) << 3),
             Bs + (size_t)g8*512);
  }
}
__device__ __forceinline__ void stage128(const unsigned short* Bt, int kB,
                                         int w, int lane, unsigned short* Bs){
#pragma unroll
  for (int i = 0; i < 2; i++){
    int g8 = i*8 + w;                  // 0..15
    int r  = g8*8 + (lane >> 3);       // 0..127
    int s  = lane & 7;
    gl_lds16(Bt + (size_t)r*VDIM + kB + ((s ^ (r & 7)) << 3),
             Bs + (size_t)g8*512);
  }
}

// swizzled B-fragment read (klocal = k within 64-chunk, multiple of 8)
__device__ __forceinline__ short8 bs_frag(const unsigned short* Bs, int c, int klocal){
  int slot = klocal >> 3;
  return *(const short8*)&Bs[(size_t)c*64 + (((slot ^ (c & 7))) << 3)];
}

// ---- MFMA chunk cores (one 64-wide K-chunk) --------------------------------
// D frag: col = lane&15, row = (lane>>4)*4 + reg   [measured: learn_hip m89]
// A in registers (prefetched same-phase as the DMA), B from swizzled Bs.
template<int NF>
__device__ __forceinline__ void mm_rA(const short8 (&a)[2][2], const unsigned short* Bs,
                                      int c0, int kb, f32x4 (&acc)[2][NF])
{
#pragma unroll
  for (int k = 0; k < 2; k++){
#pragma unroll
    for (int fn = 0; fn < NF; fn++){
      int c = c0 + fn*16;
      short8 b = bs_frag(Bs, c, k*32 + kb);
      acc[0][fn] = __builtin_amdgcn_mfma_f32_16x16x32_bf16(a[k][0], b, acc[0][fn], 0, 0, 0);
      acc[1][fn] = __builtin_amdgcn_mfma_f32_16x16x32_bf16(a[k][1], b, acc[1][fn], 0, 0, 0);
    }
  }
}
// A from XOR-swizzled LDS buf (element col ^ ((row&7)<<3)); rows rl0, rl0+16
template<int NF>
__device__ __forceinline__ void mm_lA(const unsigned short* Alds, int ldaE,
                                      const unsigned short* Bs,
                                      int rl0, int c0, int kb, int kB,
                                      f32x4 (&acc)[2][NF])
{
  int sw = (rl0 & 7) << 3;
#pragma unroll
  for (int k = 0; k < 2; k++){
    int ka = kB + k*32 + kb;
    short8 a0 = *(const short8*)&Alds[(size_t)rl0 * ldaE + (ka ^ sw)];
    short8 a1 = *(const short8*)&Alds[(size_t)(rl0+16) * ldaE + (ka ^ sw)];
#pragma unroll
    for (int fn = 0; fn < NF; fn++){
      int c = c0 + fn*16;
      short8 b = bs_frag(Bs, c, k*32 + kb);
      acc[0][fn] = __builtin_amdgcn_mfma_f32_16x16x32_bf16(a0, b, acc[0][fn], 0, 0, 0);
      acc[1][fn] = __builtin_amdgcn_mfma_f32_16x16x32_bf16(a1, b, acc[1][fn], 0, 0, 0);
    }
  }
}
// single 16-row A frag, B from global (tiny W2 panel, stage-5 only)
template<int NF, int KSZ>
__device__ __forceinline__ void mm_l1(const unsigned short* Alds, int ldaE,
                                      const unsigned short* Bt, int ldb,
                                      int rl0, int c0, int kb,
                                      f32x4 (&acc)[NF])
{
  int sw = (rl0 & 7) << 3;
#pragma unroll
  for (int k0 = 0; k0 < KSZ; k0 += 32){
    int ka = k0 + kb;
    short8 a0 = *(const short8*)&Alds[(size_t)rl0 * ldaE + (ka ^ sw)];
#pragma unroll
    for (int fn = 0; fn < NF; fn++){
      short8 b = ldb8(Bt + (size_t)(c0 + fn*16)*ldb + ka);
      acc[fn] = __builtin_amdgcn_mfma_f32_16x16x32_bf16(a0, b, acc[fn], 0, 0, 0);
    }
  }
}

// ---- merged prep + seg_build (block-partitioned) ---------------------------
__global__ __launch_bounds__(256) void prep_seg(
    const float* X, const float* IV, const int* ivars,
    const float* eW1, const float* eW2, const float* pW1, const float* pW2,
    const int* cidx, const int* eidx, const float* stren,
    unsigned short* XB,
    unsigned short* bt1, unsigned short* bt2,
    unsigned short* w1ab, unsigned short* w1c,
    unsigned short* w2bf, float* w1bcol, int* colmap,
    float* delta, float* segs)
{
  if (blockIdx.x < 1024){
    __shared__ int lc[SEGLEN];
    __shared__ int le[SEGLEN];
    __shared__ float la[SEGLEN];
    int bid = blockIdx.x;            // 64 per segment, 4 rows each
    int seg = bid >> 6;
    int rowbase = (bid & 63) * 4;
    int w = threadIdx.x >> 6, lane = threadIdx.x & 63;
    int row = rowbase + w;
    int k0 = seg * SEGLEN;
    for (int t = threadIdx.x; t < SEGLEN; t += 256){
      lc[t] = cidx[k0 + t]; le[t] = eidx[k0 + t]; la[t] = stren[k0 + t] * 0.1f;
    }
    __syncthreads();
    float r0 = (row == lane)        ? 1.f : 0.f;
    float r1 = (row == lane + 64)   ? 1.f : 0.f;
    float r2 = (row == lane + 128)  ? 1.f : 0.f;
    float r3 = (row == lane + 192)  ? 1.f : 0.f;
    for (int t = 0; t < SEGLEN; t++){
      int cs = __builtin_amdgcn_readfirstlane(lc[t]);
      int es = __builtin_amdgcn_readfirstlane(le[t]);
      float a = la[t];
      float vr;
      switch (cs >> 6){ case 0: vr = r0; break; case 1: vr = r1; break;
                        case 2: vr = r2; break; default: vr = r3; }
      float v = __shfl(vr, cs & 63, 64);
      float add = (lane == (es & 63)) ? a * v : 0.f;
      switch (es >> 6){ case 0: r0 += add; break; case 1: r1 += add; break;
                        case 2: r2 += add; break; default: r3 += add; }
    }
    float* out = segs + (size_t)seg * 65536 + (size_t)row * 256;
    out[lane] = r0; out[lane + 64] = r1; out[lane + 128] = r2; out[lane + 192] = r3;
    return;
  }
  int stride = 1024 * 256;
  int g0 = (blockIdx.x - 1024) * 256 + threadIdx.x;
  for (int i = g0; i < (BDIM * VDIM) / 8; i += stride){
    const float* p = X + (size_t)i * 8;
    f32x4 lo = *(const f32x4*)p;
    f32x4 hi = *(const f32x4*)(p + 4);
    short8 r;
    r[0]=(short)f2b(lo[0]); r[1]=(short)f2b(lo[1]); r[2]=(short)f2b(lo[2]); r[3]=(short)f2b(lo[3]);
    r[4]=(short)f2b(hi[0]); r[5]=(short)f2b(hi[1]); r[6]=(short)f2b(hi[2]); r[7]=(short)f2b(hi[3]);
    *(short8*)(XB + (size_t)i * 8) = r;
  }
  for (int i = g0; i < 65536; i += stride) bt1[i] = f2b(eW1[i]);
  for (int i = g0; i < 65536; i += stride){
    int v = i >> 8, r = i & 255;
    bt2[i] = f2b(eW2[(r >> 6) * 16384 + v * 64 + (r & 63)]);
  }
  for (int i = g0; i < 32768; i += stride){
    int o = i >> 8, v = i & 255;
    w1ab[i] = f2b(pW1[o*768 + v] + pW1[o*768 + 256 + v]);
    w1c[i]  = f2b(pW1[o*768 + 512 + v]);
  }
  for (int i = g0; i < 8192; i += stride) w2bf[i] = f2b(pW2[i]);
  for (int i = g0; i < 512; i += stride){
    int o = i >> 2, k = i & 3;
    w1bcol[i] = pW1[o*768 + 256 + ivars[k]];
  }
  for (int i = g0; i < VDIM; i += stride){
    int m = -1;
#pragma unroll
    for (int k = 0; k < KVAR; k++) if (ivars[k] == i) m = k;
    colmap[i] = m;
  }
  for (int i = g0; i < BDIM * KVAR; i += stride){
    int b = i >> 2, k = i & 3;
    delta[i] = IV[i] - X[(size_t)b * VDIM + ivars[k]];
  }
}

// ---- combine: Out[m] = S[4m]*S[4m+1]*S[4m+2]*S[4m+3], 4 rows per block -----
__global__ __launch_bounds__(256) void combine4(const float* S, float* Out)
{
  int m = blockIdx.x >> 6;
  int rb = (blockIdx.x & 63) * 4;
  int c = threadIdx.x;
  __shared__ float v[4][256];
  const float* base = S + (size_t)m * 4 * 65536;
#pragma unroll
  for (int r = 0; r < 4; r++) v[r][c] = base[(size_t)(rb + r) * 256 + c];
  __syncthreads();
  for (int p = 1; p < 4; p++){
    const float* Bm = base + (size_t)p * 65536;
    float a0 = 0.f, a1 = 0.f, a2 = 0.f, a3 = 0.f;
    for (int k = 0; k < 256; k += 4){
      f32x4 v0 = *(const f32x4*)&v[0][k];
      f32x4 v1 = *(const f32x4*)&v[1][k];
      f32x4 v2 = *(const f32x4*)&v[2][k];
      f32x4 v3 = *(const f32x4*)&v[3][k];
#pragma unroll
      for (int j = 0; j < 4; j++){
        float bk = Bm[(size_t)(k + j) * 256 + c];
        a0 += v0[j] * bk; a1 += v1[j] * bk; a2 += v2[j] * bk; a3 += v3[j] * bk;
      }
    }
    __syncthreads();
    v[0][c] = a0; v[1][c] = a1; v[2][c] = a2; v[3][c] = a3;
    __syncthreads();
  }
#pragma unroll
  for (int r = 0; r < 4; r++) Out[(size_t)m * 65536 + (size_t)(rb + r) * 256 + c] = v[r][c];
}

// ---- M = R*R*R, written transposed bf16: Mt[c][r] --------------------------
__global__ __launch_bounds__(256) void powM(const float* R, unsigned short* Mt)
{
  int rb = blockIdx.x * 4;
  int c = threadIdx.x;
  __shared__ float v[4][256];
#pragma unroll
  for (int r = 0; r < 4; r++) v[r][c] = R[(size_t)(rb + r) * 256 + c];
  __syncthreads();
  for (int p = 0; p < 2; p++){
    float a0 = 0.f, a1 = 0.f, a2 = 0.f, a3 = 0.f;
    for (int k = 0; k < 256; k += 4){
      f32x4 v0 = *(const f32x4*)&v[0][k];
      f32x4 v1 = *(const f32x4*)&v[1][k];
      f32x4 v2 = *(const f32x4*)&v[2][k];
      f32x4 v3 = *(const f32x4*)&v[3][k];
#pragma unroll
      for (int j = 0; j < 4; j++){
        float bk = R[(size_t)(k + j) * 256 + c];
        a0 += v0[j] * bk; a1 += v1[j] * bk; a2 += v2[j] * bk; a3 += v3[j] * bk;
      }
    }
    __syncthreads();
    v[0][c] = a0; v[1][c] = a1; v[2][c] = a2; v[3][c] = a3;
    __syncthreads();
  }
#pragma unroll
  for (int r = 0; r < 4; r++) Mt[(size_t)c * 256 + (rb + r)] = f2b(v[r][c]);
}

// ---- MEGA: H -> eff -> final -> P1 -> P2/plaus + impact --------------------
// 64-row stripe per block, 8 waves (2 rowg x 4 colg), wave tile 32x64.
// B panels staged into LDS per 64-wide K-chunk via global_load_lds
// (source-swizzled; conflict-free swizzled reads). A for global-A stages is
// prefetched into regs in the same phase -> one vmcnt(0)+barrier covers both.
__global__ __launch_bounds__(512, 4) void mega(
    const float* IV, const unsigned short* XB,
    const unsigned short* Bt1, const unsigned short* Bt2, const unsigned short* Mt,
    const unsigned short* W1ab, const unsigned short* W1c, const unsigned short* W2bf,
    const float* eb1, const float* eb2, const float* delta, const int* colmap,
    const float* w1bcol, const float* pb1, const float* pb2,
    const float* W3, const float* pb3,
    float* effOut, float* outF, float* plausOut, float* impOut)
{
  __shared__ unsigned short buf[64 * 256];   // 32 KB, stage-to-stage scratch
  __shared__ unsigned short Bs[256 * 64];    // 32 KB, B-panel K-chunk
  __shared__ float impLds[64 * 4];
  int tid = threadIdx.x, w = tid >> 6, lane = tid & 63;
  int rowg = w >> 2, colg = w & 3;
  int rowBlk = blockIdx.x * 64;
  int rl0 = rowg * 32 + (lane & 15);
  int r0 = rowBlk + rl0;
  int colBase = colg * 64;
  int c0 = colBase + (lane & 15);
  int kb = (lane >> 4) * 8;
  f32x4 acc[2][4];

  // ---- stage 1: H = relu(XB@W1^T + b1) * |delta_k| -> buf (swizzled bf16)
#pragma unroll
  for (int fm = 0; fm < 2; fm++)
#pragma unroll
    for (int fn = 0; fn < 4; fn++) acc[fm][fn] = (f32x4){0.f,0.f,0.f,0.f};
  for (int kc = 0; kc < 4; kc++){
    int kB = kc * 64;
    stage256(Bt1, kB, w, lane, Bs);
    short8 a[2][2];
#pragma unroll
    for (int k = 0; k < 2; k++)
#pragma unroll
      for (int m = 0; m < 2; m++)
        a[k][m] = ldb8(XB + (size_t)(r0 + m*16)*VDIM + kB + k*32 + kb);
    __syncthreads();
    __builtin_amdgcn_s_setprio(1);
    mm_rA<4>(a, Bs, c0, kb, acc);
    __builtin_amdgcn_s_setprio(0);
    __syncthreads();
  }
  {
    float b1v[4];
#pragma unroll
    for (int fn = 0; fn < 4; fn++) b1v[fn] = eb1[colBase + fn*16 + (lane & 15)];
#pragma unroll
    for (int fm = 0; fm < 2; fm++)
#pragma unroll
      for (int i = 0; i < 4; i++){
        int rl = rowg*32 + fm*16 + (lane >> 4)*4 + i;
        int gr = rowBlk + rl;
        float mg = fabsf(delta[gr*4 + colg]);
        int sw = (rl & 7) << 3;
#pragma unroll
        for (int fn = 0; fn < 4; fn++){
          int col = colBase + fn*16 + (lane & 15);
          float h = acc[fm][fn][i] + b1v[fn];
          h = h > 0.f ? h : 0.f;
          buf[(size_t)rl*256 + (col ^ sw)] = f2b(h * mg);
        }
      }
  }
  __syncthreads();

  // ---- stage 2: eff = Hs@W2f + sum|d_k| b2[k] ; d0 -> buf
#pragma unroll
  for (int fm = 0; fm < 2; fm++)
#pragma unroll
    for (int fn = 0; fn < 4; fn++) acc[fm][fn] = (f32x4){0.f,0.f,0.f,0.f};
  for (int kc = 0; kc < 4; kc++){
    int kB = kc * 64;
    stage256(Bt2, kB, w, lane, Bs);
    __syncthreads();
    __builtin_amdgcn_s_setprio(1);
    mm_lA<4>(buf, 256, Bs, rl0, c0, kb, kB, acc);
    __builtin_amdgcn_s_setprio(0);
    __syncthreads();
  }
  {
    float bb0[4], bb1[4], bb2[4], bb3[4];
    int imv[4];
#pragma unroll
    for (int fn = 0; fn < 4; fn++){
      int col = colBase + fn*16 + (lane & 15);
      bb0[fn] = eb2[col]; bb1[fn] = eb2[256 + col];
      bb2[fn] = eb2[512 + col]; bb3[fn] = eb2[768 + col];
      imv[fn] = colmap[col];
    }
#pragma unroll
    for (int fm = 0; fm < 2; fm++)
#pragma unroll
      for (int i = 0; i < 4; i++){
        int rl = rowg*32 + fm*16 + (lane >> 4)*4 + i;
        int gr = rowBlk + rl;
        f32x4 dl = *(const f32x4*)&delta[gr*4];
        float d0a = fabsf(dl[0]), d1a = fabsf(dl[1]), d2a = fabsf(dl[2]), d3a = fabsf(dl[3]);
        int sw = (rl & 7) << 3;
#pragma unroll
        for (int fn = 0; fn < 4; fn++){
          int col = colBase + fn*16 + (lane & 15);
          float eff = acc[fm][fn][i] + d0a*bb0[fn] + d1a*bb1[fn] + d2a*bb2[fn] + d3a*bb3[fn];
          size_t idx = (size_t)gr*VDIM + col;
          __builtin_nontemporal_store(eff, &effOut[idx]);
          float base = (imv[fn] >= 0) ? IV[gr*4 + imv[fn]] : b2f(XB[idx]);
          buf[(size_t)rl*256 + (col ^ sw)] = f2b(base + eff);
        }
      }
  }
  __syncthreads();

  // ---- stage 3: final = Ds@M -> outF ; Fin -> buf ; impact partials -> LDS
#pragma unroll
  for (int fm = 0; fm < 2; fm++)
#pragma unroll
    for (int fn = 0; fn < 4; fn++) acc[fm][fn] = (f32x4){0.f,0.f,0.f,0.f};
  for (int kc = 0; kc < 4; kc++){
    int kB = kc * 64;
    stage256(Mt, kB, w, lane, Bs);
    __syncthreads();
    __builtin_amdgcn_s_setprio(1);
    mm_lA<4>(buf, 256, Bs, rl0, c0, kb, kB, acc);
    __builtin_amdgcn_s_setprio(0);
    __syncthreads();
  }
  {
#pragma unroll
    for (int fm = 0; fm < 2; fm++)
#pragma unroll
      for (int i = 0; i < 4; i++){
        int rl = rowg*32 + fm*16 + (lane >> 4)*4 + i;
        int gr = rowBlk + rl;
        int sw = (rl & 7) << 3;
        float ss = 0.f;
#pragma unroll
        for (int fn = 0; fn < 4; fn++){
          int col = colBase + fn*16 + (lane & 15);
          size_t idx = (size_t)gr*VDIM + col;
          float fv = acc[fm][fn][i];
          __builtin_nontemporal_store(fv, &outF[idx]);
          buf[(size_t)rl*256 + (col ^ sw)] = f2b(fv);
          float d = fv - b2f(XB[idx]);
          ss += d * d;
        }
        ss += __shfl_xor(ss, 1, 64); ss += __shfl_xor(ss, 2, 64);
        ss += __shfl_xor(ss, 4, 64); ss += __shfl_xor(ss, 8, 64);
        if ((lane & 15) == 0) impLds[rl*4 + colg] = ss;
      }
  }
  __syncthreads();

  // ---- stage 4: P1 = relu(XB@W1ab^T + Fin@W1c^T + delta corr + b1) -> buf
  {
    f32x4 a4[2][2];
#pragma unroll
    for (int fm = 0; fm < 2; fm++)
#pragma unroll
      for (int fn = 0; fn < 2; fn++) a4[fm][fn] = (f32x4){0.f,0.f,0.f,0.f};
    int c4 = colg * 32 + (lane & 15);
    for (int kc = 0; kc < 4; kc++){
      int kB = kc * 64;
      stage128(W1ab, kB, w, lane, Bs);           // rows 0..127
      stage128(W1c,  kB, w, lane, Bs + 8192);    // rows 128..255 (panel-local swz)
      short8 a[2][2];
#pragma unroll
      for (int k = 0; k < 2; k++)
#pragma unroll
        for (int m = 0; m < 2; m++)
          a[k][m] = ldb8(XB + (size_t)(r0 + m*16)*VDIM + kB + k*32 + kb);
      __syncthreads();
      __builtin_amdgcn_s_setprio(1);
      mm_rA<2>(a, Bs, c4, kb, a4);
      mm_lA<2>(buf, 256, Bs + 8192, rl0, c4, kb, kB, a4);
      __builtin_amdgcn_s_setprio(0);
      __syncthreads();
    }
    float bv[2];
    f32x4 wb[2];
#pragma unroll
    for (int fn = 0; fn < 2; fn++){
      int col = colg*32 + fn*16 + (lane & 15);
      bv[fn] = pb1[col];
      wb[fn] = *(const f32x4*)&w1bcol[col*4];
    }
#pragma unroll
    for (int fm = 0; fm < 2; fm++)
#pragma unroll
      for (int i = 0; i < 4; i++){
        int rl = rowg*32 + fm*16 + (lane >> 4)*4 + i;
        int gr = rowBlk + rl;
        f32x4 dl = *(const f32x4*)&delta[gr*4];
        int sw = (rl & 7) << 3;
#pragma unroll
        for (int fn = 0; fn < 2; fn++){
          int col = colg*32 + fn*16 + (lane & 15);
          float p = a4[fm][fn][i] + bv[fn]
                  + dl[0]*wb[fn][0] + dl[1]*wb[fn][1] + dl[2]*wb[fn][2] + dl[3]*wb[fn][3];
          p = p > 0.f ? p : 0.f;
          buf[(size_t)rl*128 + (col ^ sw)] = f2b(p);
        }
      }
  }
  __syncthreads();

  // ---- stage 5: P2 = relu(P1@W2^T + b2); plaus; impact finish
  if (w < 4){
    int rl0b = w * 16 + (lane & 15);
    f32x4 a2[4];
#pragma unroll
    for (int fn = 0; fn < 4; fn++) a2[fn] = (f32x4){0.f,0.f,0.f,0.f};
    mm_l1<4, 128>(buf, 128, W2bf, 128, rl0b, (lane & 15), kb, a2);
    float b2v[4], w3v[4];
#pragma unroll
    for (int fn = 0; fn < 4; fn++){
      int col = fn*16 + (lane & 15);
      b2v[fn] = pb2[col]; w3v[fn] = W3[col];
    }
    float b3v = pb3[0];
#pragma unroll
    for (int i = 0; i < 4; i++){
      float s = 0.f;
#pragma unroll
      for (int fn = 0; fn < 4; fn++){
        float p2 = a2[fn][i] + b2v[fn];
        p2 = p2 > 0.f ? p2 : 0.f;
        s += p2 * w3v[fn];
      }
      s += __shfl_xor(s, 1, 64); s += __shfl_xor(s, 2, 64);
      s += __shfl_xor(s, 4, 64); s += __shfl_xor(s, 8, 64);
      if ((lane & 15) == 0){
        int gr = rowBlk + w*16 + (lane >> 4)*4 + i;
        plausOut[gr] = 1.f / (1.f + expf(-(s + b3v)));
      }
    }
  } else if (w == 4){
    f32x4 v = *(const f32x4*)&impLds[lane * 4];
    impOut[rowBlk + lane] = sqrtf(v[0] + v[1] + v[2] + v[3]);
  }
}

// ---- workspace layout (bytes) ----------------------------------------------
#define WS_XB     ((size_t)0)           // 16 MB
#define WS_DELTA  ((size_t)16777216)    // 512 KB
#define WS_SEG    ((size_t)17301504)    // 4 MB
#define WS_T2     ((size_t)21495808)    // 1 MB
#define WS_R      ((size_t)22544384)    // 256 KB
#define WS_MT     ((size_t)22806528)    // 128 KB
#define WS_BT1    ((size_t)22937600)    // 128 KB
#define WS_BT2    ((size_t)23068672)    // 128 KB
#define WS_W1AB   ((size_t)23199744)    // 64 KB
#define WS_W1C    ((size_t)23265280)    // 64 KB
#define WS_W2BF   ((size_t)23330816)    // 16 KB
#define WS_W1BCOL ((size_t)23347200)    // 2 KB
#define WS_COLMAP ((size_t)23349248)    // 1 KB

extern "C" void kernel_launch(void* const* d_in, const int* in_sizes, int n_in,
                              void* d_out, int out_size, void* d_ws, size_t ws_size,
                              hipStream_t stream)
{
  const float* X     = (const float*)d_in[0];
  const float* IV    = (const float*)d_in[1];
  const float* STR   = (const float*)d_in[2];
  const int*   IVARS = (const int*)d_in[3];
  const int*   CIDX  = (const int*)d_in[4];
  const int*   EIDX  = (const int*)d_in[5];
  const float* EW1   = (const float*)d_in[6];
  const float* EB1   = (const float*)d_in[7];
  const float* EW2   = (const float*)d_in[8];
  const float* EB2   = (const float*)d_in[9];
  const float* PW1   = (const float*)d_in[10];
  const float* PB1   = (const float*)d_in[11];
  const float* PW2   = (const float*)d_in[12];
  const float* PB2   = (const float*)d_in[13];
  const float* PW3   = (const float*)d_in[14];
  const float* PB3   = (const float*)d_in[15];

  char* ws = (char*)d_ws;
  unsigned short* XB     = (unsigned short*)(ws + WS_XB);
  float*          DELTA  = (float*)(ws + WS_DELTA);
  float*          SEG    = (float*)(ws + WS_SEG);
  float*          T2     = (float*)(ws + WS_T2);
  float*          Rm     = (float*)(ws + WS_R);
  unsigned short* MT     = (unsigned short*)(ws + WS_MT);
  unsigned short* BT1    = (unsigned short*)(ws + WS_BT1);
  unsigned short* BT2    = (unsigned short*)(ws + WS_BT2);
  unsigned short* W1AB   = (unsigned short*)(ws + WS_W1AB);
  unsigned short* W1C    = (unsigned short*)(ws + WS_W1C);
  unsigned short* W2BF   = (unsigned short*)(ws + WS_W2BF);
  float*          W1BCOL = (float*)(ws + WS_W1BCOL);
  int*            COLMAP = (int*)(ws + WS_COLMAP);

  float* outF   = (float*)d_out;                       // final_cf  [B,V]
  float* outEff = outF + (size_t)BDIM * VDIM;          // effects   [B,V]
  float* outPl  = outEff + (size_t)BDIM * VDIM;        // plaus     [B]
  float* outIm  = outPl + BDIM;                        // impact    [B]

  prep_seg<<<2048, 256, 0, stream>>>(X, IV, IVARS, EW1, EW2, PW1, PW2,
                                     CIDX, EIDX, STR,
                                     XB, BT1, BT2, W1AB, W1C, W2BF, W1BCOL, COLMAP,
                                     DELTA, SEG);
  combine4<<<256, 256, 0, stream>>>(SEG, T2);    // 16 segs -> 4
  combine4<<<64, 256, 0, stream>>>(T2, Rm);      // 4 -> R
  powM<<<64, 256, 0, stream>>>(Rm, MT);          // M = R^3, transposed bf16

  mega<<<512, 512, 0, stream>>>(IV, XB, BT1, BT2, MT, W1AB, W1C, W2BF,
                                EB1, EB2, DELTA, COLMAP, W1BCOL,
                                PB1, PB2, PW3, PB3,
                                outEff, outF, outPl, outIm);

  (void)in_sizes; (void)n_in; (void)out_size; (void)ws_size;
}

// Round 3
// 193.469 us; speedup vs baseline: 1.2930x; 1.0614x over previous
//
#include <hip/hip_runtime.h>

#define BDIM 32768
#define VDIM 256
#define KVAR 4
#define EDIM 2048
#define SEGS 16
#define SEGLEN 128   // EDIM / SEGS

typedef __attribute__((ext_vector_type(8))) short short8;
typedef __attribute__((ext_vector_type(4))) float f32x4;

__device__ __forceinline__ unsigned short f2b(float f){
  union { float f; unsigned u; } v; v.f = f;
  unsigned r = v.u + 0x7FFFu + ((v.u >> 16) & 1u);   // round-to-nearest-even
  return (unsigned short)(r >> 16);
}
__device__ __forceinline__ float b2f(unsigned short h){
  union { unsigned u; float f; } v; v.u = ((unsigned)h) << 16;
  return v.f;
}
__device__ __forceinline__ short8 ldb8(const unsigned short* p){
  return *(const short8*)p;
}

// async 16B global -> LDS (dest = wave-uniform base + lane*16)
__device__ __forceinline__ void gl_lds16(const unsigned short* g, unsigned short* l){
  __builtin_amdgcn_global_load_lds(
      (const __attribute__((address_space(1))) unsigned int*)g,
      (__attribute__((address_space(3))) unsigned int*)l, 16, 0, 0);
}

// ---- LDS staging -----------------------------------------------------------
// Panel layout: row r -> 64 k-elems (128 B = 8 slots of 16B); LDS slot s holds
// global slot (s ^ (r&7))  [source-swizzled so swizzled reads are conflict-free]
// One wave issue = 8 rows (64 lanes x 16B = 1 KB).
__device__ __forceinline__ void stage256(const unsigned short* Bt, int kB,
                                         int w, int lane, unsigned short* Bs){
#pragma unroll
  for (int i = 0; i < 4; i++){
    int g8 = i*8 + w;                  // row-group of 8 (0..31)
    int r  = g8*8 + (lane >> 3);
    int s  = lane & 7;
    gl_lds16(Bt + (size_t)r*VDIM + kB + ((s ^ (r & 7)) << 3),
             Bs + (size_t)g8*512);
  }
}
__device__ __forceinline__ void stage128(const unsigned short* Bt, int kB,
                                         int w, int lane, unsigned short* Bs){
#pragma unroll
  for (int i = 0; i < 2; i++){
    int g8 = i*8 + w;                  // 0..15
    int r  = g8*8 + (lane >> 3);       // 0..127
    int s  = lane & 7;
    gl_lds16(Bt + (size_t)r*VDIM + kB + ((s ^ (r & 7)) << 3),
             Bs + (size_t)g8*512);
  }
}
// XB stripe k-chunk: 64 rows x 64 k -> 8 KB, one DMA per wave
__device__ __forceinline__ void stage64xb(const unsigned short* XBg, int rowBlk, int kB,
                                          int w, int lane, unsigned short* xbs){
  int r = w*8 + (lane >> 3);           // 0..63
  int s = lane & 7;
  gl_lds16(XBg + (size_t)(rowBlk + r)*VDIM + kB + ((s ^ (r & 7)) << 3),
           xbs + (size_t)w*512);
}

// swizzled fragment read (klocal = k within 64-chunk, multiple of 8)
__device__ __forceinline__ short8 bs_frag(const unsigned short* Bs, int c, int klocal){
  int slot = klocal >> 3;
  return *(const short8*)&Bs[(size_t)c*64 + ((slot ^ (c & 7)) << 3)];
}

// ---- MFMA chunk cores (one 64-wide K-chunk) --------------------------------
// D frag: col = lane&15, row = (lane>>4)*4 + reg   [measured: learn_hip m89]
// A from xbs (64-elem swizzled rows), B from swizzled Bs.
template<int NF>
__device__ __forceinline__ void mm_xA(const unsigned short* xbs, const unsigned short* Bs,
                                      int rl0, int c0, int kb, f32x4 (&acc)[2][NF])
{
  int sw = (rl0 & 7) << 3;             // (rl0+16)&7 == rl0&7
#pragma unroll
  for (int k = 0; k < 2; k++){
    int kl = k*32 + kb;
    short8 a0 = *(const short8*)&xbs[(size_t)rl0*64 + (kl ^ sw)];
    short8 a1 = *(const short8*)&xbs[(size_t)(rl0+16)*64 + (kl ^ sw)];
#pragma unroll
    for (int fn = 0; fn < NF; fn++){
      short8 b = bs_frag(Bs, c0 + fn*16, kl);
      acc[0][fn] = __builtin_amdgcn_mfma_f32_16x16x32_bf16(a0, b, acc[0][fn], 0, 0, 0);
      acc[1][fn] = __builtin_amdgcn_mfma_f32_16x16x32_bf16(a1, b, acc[1][fn], 0, 0, 0);
    }
  }
}
// A from XOR-swizzled LDS buf (element col ^ ((row&7)<<3), 256-elem rows)
template<int NF>
__device__ __forceinline__ void mm_lA(const unsigned short* Alds, int ldaE,
                                      const unsigned short* Bs,
                                      int rl0, int c0, int kb, int kB,
                                      f32x4 (&acc)[2][NF])
{
  int sw = (rl0 & 7) << 3;
#pragma unroll
  for (int k = 0; k < 2; k++){
    int ka = kB + k*32 + kb;
    short8 a0 = *(const short8*)&Alds[(size_t)rl0 * ldaE + (ka ^ sw)];
    short8 a1 = *(const short8*)&Alds[(size_t)(rl0+16) * ldaE + (ka ^ sw)];
#pragma unroll
    for (int fn = 0; fn < NF; fn++){
      short8 b = bs_frag(Bs, c0 + fn*16, k*32 + kb);
      acc[0][fn] = __builtin_amdgcn_mfma_f32_16x16x32_bf16(a0, b, acc[0][fn], 0, 0, 0);
      acc[1][fn] = __builtin_amdgcn_mfma_f32_16x16x32_bf16(a1, b, acc[1][fn], 0, 0, 0);
    }
  }
}
// single 16-row A frag, B from global (tiny W2 panel, stage-5 only)
template<int NF, int KSZ>
__device__ __forceinline__ void mm_l1(const unsigned short* Alds, int ldaE,
                                      const unsigned short* Bt, int ldb,
                                      int rl0, int c0, int kb,
                                      f32x4 (&acc)[NF])
{
  int sw = (rl0 & 7) << 3;
#pragma unroll
  for (int k0 = 0; k0 < KSZ; k0 += 32){
    int ka = k0 + kb;
    short8 a0 = *(const short8*)&Alds[(size_t)rl0 * ldaE + (ka ^ sw)];
#pragma unroll
    for (int fn = 0; fn < NF; fn++){
      short8 b = ldb8(Bt + (size_t)(c0 + fn*16)*ldb + ka);
      acc[fn] = __builtin_amdgcn_mfma_f32_16x16x32_bf16(a0, b, acc[fn], 0, 0, 0);
    }
  }
}

// ---- merged prep + seg_build (block-partitioned) ---------------------------
__global__ __launch_bounds__(256) void prep_seg(
    const float* X, const float* IV, const int* ivars,
    const float* eW1, const float* eW2, const float* pW1, const float* pW2,
    const int* cidx, const int* eidx, const float* stren,
    unsigned short* XB,
    unsigned short* bt1, unsigned short* bt2,
    unsigned short* w1ab, unsigned short* w1c,
    unsigned short* w2bf, float* w1bcol, int* colmap,
    float* delta, float* segs)
{
  if (blockIdx.x < 1024){
    __shared__ int lc[SEGLEN];
    __shared__ int le[SEGLEN];
    __shared__ float la[SEGLEN];
    int bid = blockIdx.x;            // 64 per segment, 4 rows each
    int seg = bid >> 6;
    int rowbase = (bid & 63) * 4;
    int w = threadIdx.x >> 6, lane = threadIdx.x & 63;
    int row = rowbase + w;
    int k0 = seg * SEGLEN;
    for (int t = threadIdx.x; t < SEGLEN; t += 256){
      lc[t] = cidx[k0 + t]; le[t] = eidx[k0 + t]; la[t] = stren[k0 + t] * 0.1f;
    }
    __syncthreads();
    float r0 = (row == lane)        ? 1.f : 0.f;
    float r1 = (row == lane + 64)   ? 1.f : 0.f;
    float r2 = (row == lane + 128)  ? 1.f : 0.f;
    float r3 = (row == lane + 192)  ? 1.f : 0.f;
    for (int t = 0; t < SEGLEN; t++){
      int cs = __builtin_amdgcn_readfirstlane(lc[t]);
      int es = __builtin_amdgcn_readfirstlane(le[t]);
      float a = la[t];
      float vr;
      switch (cs >> 6){ case 0: vr = r0; break; case 1: vr = r1; break;
                        case 2: vr = r2; break; default: vr = r3; }
      float v = __shfl(vr, cs & 63, 64);
      float add = (lane == (es & 63)) ? a * v : 0.f;
      switch (es >> 6){ case 0: r0 += add; break; case 1: r1 += add; break;
                        case 2: r2 += add; break; default: r3 += add; }
    }
    float* out = segs + (size_t)seg * 65536 + (size_t)row * 256;
    out[lane] = r0; out[lane + 64] = r1; out[lane + 128] = r2; out[lane + 192] = r3;
    return;
  }
  int stride = 1024 * 256;
  int g0 = (blockIdx.x - 1024) * 256 + threadIdx.x;
  for (int i = g0; i < (BDIM * VDIM) / 8; i += stride){
    const float* p = X + (size_t)i * 8;
    f32x4 lo = *(const f32x4*)p;
    f32x4 hi = *(const f32x4*)(p + 4);
    short8 r;
    r[0]=(short)f2b(lo[0]); r[1]=(short)f2b(lo[1]); r[2]=(short)f2b(lo[2]); r[3]=(short)f2b(lo[3]);
    r[4]=(short)f2b(hi[0]); r[5]=(short)f2b(hi[1]); r[6]=(short)f2b(hi[2]); r[7]=(short)f2b(hi[3]);
    *(short8*)(XB + (size_t)i * 8) = r;
  }
  for (int i = g0; i < 65536; i += stride) bt1[i] = f2b(eW1[i]);
  for (int i = g0; i < 65536; i += stride){
    int v = i >> 8, r = i & 255;
    bt2[i] = f2b(eW2[(r >> 6) * 16384 + v * 64 + (r & 63)]);
  }
  for (int i = g0; i < 32768; i += stride){
    int o = i >> 8, v = i & 255;
    w1ab[i] = f2b(pW1[o*768 + v] + pW1[o*768 + 256 + v]);
    w1c[i]  = f2b(pW1[o*768 + 512 + v]);
  }
  for (int i = g0; i < 8192; i += stride) w2bf[i] = f2b(pW2[i]);
  for (int i = g0; i < 512; i += stride){
    int o = i >> 2, k = i & 3;
    w1bcol[i] = pW1[o*768 + 256 + ivars[k]];
  }
  for (int i = g0; i < VDIM; i += stride){
    int m = -1;
#pragma unroll
    for (int k = 0; k < KVAR; k++) if (ivars[k] == i) m = k;
    colmap[i] = m;
  }
  for (int i = g0; i < BDIM * KVAR; i += stride){
    int b = i >> 2, k = i & 3;
    delta[i] = IV[i] - X[(size_t)b * VDIM + ivars[k]];
  }
}

// ---- combine: Out[m] = S[4m]*S[4m+1]*S[4m+2]*S[4m+3], 4 rows per block -----
__global__ __launch_bounds__(256) void combine4(const float* S, float* Out)
{
  int m = blockIdx.x >> 6;
  int rb = (blockIdx.x & 63) * 4;
  int c = threadIdx.x;
  __shared__ float v[4][256];
  const float* base = S + (size_t)m * 4 * 65536;
#pragma unroll
  for (int r = 0; r < 4; r++) v[r][c] = base[(size_t)(rb + r) * 256 + c];
  __syncthreads();
  for (int p = 1; p < 4; p++){
    const float* Bm = base + (size_t)p * 65536;
    float a0 = 0.f, a1 = 0.f, a2 = 0.f, a3 = 0.f;
    for (int k = 0; k < 256; k += 4){
      f32x4 v0 = *(const f32x4*)&v[0][k];
      f32x4 v1 = *(const f32x4*)&v[1][k];
      f32x4 v2 = *(const f32x4*)&v[2][k];
      f32x4 v3 = *(const f32x4*)&v[3][k];
#pragma unroll
      for (int j = 0; j < 4; j++){
        float bk = Bm[(size_t)(k + j) * 256 + c];
        a0 += v0[j] * bk; a1 += v1[j] * bk; a2 += v2[j] * bk; a3 += v3[j] * bk;
      }
    }
    __syncthreads();
    v[0][c] = a0; v[1][c] = a1; v[2][c] = a2; v[3][c] = a3;
    __syncthreads();
  }
#pragma unroll
  for (int r = 0; r < 4; r++) Out[(size_t)m * 65536 + (size_t)(rb + r) * 256 + c] = v[r][c];
}

// ---- M = R*R*R, written transposed bf16: Mt[c][r] --------------------------
__global__ __launch_bounds__(256) void powM(const float* R, unsigned short* Mt)
{
  int rb = blockIdx.x * 4;
  int c = threadIdx.x;
  __shared__ float v[4][256];
#pragma unroll
  for (int r = 0; r < 4; r++) v[r][c] = R[(size_t)(rb + r) * 256 + c];
  __syncthreads();
  for (int p = 0; p < 2; p++){
    float a0 = 0.f, a1 = 0.f, a2 = 0.f, a3 = 0.f;
    for (int k = 0; k < 256; k += 4){
      f32x4 v0 = *(const f32x4*)&v[0][k];
      f32x4 v1 = *(const f32x4*)&v[1][k];
      f32x4 v2 = *(const f32x4*)&v[2][k];
      f32x4 v3 = *(const f32x4*)&v[3][k];
#pragma unroll
      for (int j = 0; j < 4; j++){
        float bk = R[(size_t)(k + j) * 256 + c];
        a0 += v0[j] * bk; a1 += v1[j] * bk; a2 += v2[j] * bk; a3 += v3[j] * bk;
      }
    }
    __syncthreads();
    v[0][c] = a0; v[1][c] = a1; v[2][c] = a2; v[3][c] = a3;
    __syncthreads();
  }
#pragma unroll
  for (int r = 0; r < 4; r++) Mt[(size_t)c * 256 + (rb + r)] = f2b(v[r][c]);
}

// ---- MEGA: H -> eff -> final -> P1 -> P2/plaus + impact --------------------
// 64-row stripe per block, 8 waves (2 rowg x 4 colg), wave tile 32x64.
// ALL global reads on the chunk critical path are coalesced global_load_lds
// (B panels 32KB + XB chunk 8KB, both source-swizzled). XB base values for the
// stage-2 base add and stage-3 impact are captured ONCE into registers from
// LDS (chunk kc == colg in stage 1). Plain stores (nt removed: nt acks from
// HBM at every epilogue barrier's vmcnt(0) drain => ~25us serialized).
__global__ __launch_bounds__(512, 4) void mega(
    const float* IV, const unsigned short* XB,
    const unsigned short* Bt1, const unsigned short* Bt2, const unsigned short* Mt,
    const unsigned short* W1ab, const unsigned short* W1c, const unsigned short* W2bf,
    const float* eb1, const float* eb2, const float* delta, const int* colmap,
    const float* w1bcol, const float* pb1, const float* pb2,
    const float* W3, const float* pb3,
    float* effOut, float* outF, float* plausOut, float* impOut)
{
  __shared__ unsigned short buf[64 * 256];   // 32 KB, stage-to-stage scratch
  __shared__ unsigned short Bs[256 * 64];    // 32 KB, B-panel K-chunk
  __shared__ unsigned short xbs[64 * 64];    // 8 KB, XB stripe K-chunk
  __shared__ float impLds[64 * 4];
  int tid = threadIdx.x, w = tid >> 6, lane = tid & 63;
  int rowg = w >> 2, colg = w & 3;
  int rowBlk = blockIdx.x * 64;
  int rl0 = rowg * 32 + (lane & 15);
  int colBase = colg * 64;
  int c0 = colBase + (lane & 15);
  int kb = (lane >> 4) * 8;
  f32x4 acc[2][4];
  unsigned short xcap[2][4][4];              // XB at this thread's D positions

  // ---- stage 1: H = relu(XB@W1^T + b1) * |delta_k| -> buf (swizzled bf16)
#pragma unroll
  for (int fm = 0; fm < 2; fm++)
#pragma unroll
    for (int fn = 0; fn < 4; fn++) acc[fm][fn] = (f32x4){0.f,0.f,0.f,0.f};
  for (int kc = 0; kc < 4; kc++){
    int kB = kc * 64;
    stage256(Bt1, kB, w, lane, Bs);
    stage64xb(XB, rowBlk, kB, w, lane, xbs);
    __syncthreads();
    __builtin_amdgcn_s_setprio(1);
    mm_xA<4>(xbs, Bs, rl0, c0, kb, acc);
    __builtin_amdgcn_s_setprio(0);
    if (colg == kc){                         // capture XB at D positions
#pragma unroll
      for (int fm = 0; fm < 2; fm++)
#pragma unroll
        for (int i = 0; i < 4; i++){
          int rl = rowg*32 + fm*16 + (lane >> 4)*4 + i;
          int sw = (rl & 7) << 3;
#pragma unroll
          for (int fn = 0; fn < 4; fn++){
            int lc = fn*16 + (lane & 15);
            xcap[fm][i][fn] = xbs[(size_t)rl*64 + (lc ^ sw)];
          }
        }
    }
    __syncthreads();
  }
  {
    float b1v[4];
#pragma unroll
    for (int fn = 0; fn < 4; fn++) b1v[fn] = eb1[colBase + fn*16 + (lane & 15)];
#pragma unroll
    for (int fm = 0; fm < 2; fm++)
#pragma unroll
      for (int i = 0; i < 4; i++){
        int rl = rowg*32 + fm*16 + (lane >> 4)*4 + i;
        int gr = rowBlk + rl;
        float mg = fabsf(delta[gr*4 + colg]);
        int sw = (rl & 7) << 3;
#pragma unroll
        for (int fn = 0; fn < 4; fn++){
          int col = colBase + fn*16 + (lane & 15);
          float h = acc[fm][fn][i] + b1v[fn];
          h = h > 0.f ? h : 0.f;
          buf[(size_t)rl*256 + (col ^ sw)] = f2b(h * mg);
        }
      }
  }
  __syncthreads();

  // ---- stage 2: eff = Hs@W2f + sum|d_k| b2[k] ; d0 -> buf
#pragma unroll
  for (int fm = 0; fm < 2; fm++)
#pragma unroll
    for (int fn = 0; fn < 4; fn++) acc[fm][fn] = (f32x4){0.f,0.f,0.f,0.f};
  for (int kc = 0; kc < 4; kc++){
    int kB = kc * 64;
    stage256(Bt2, kB, w, lane, Bs);
    __syncthreads();
    __builtin_amdgcn_s_setprio(1);
    mm_lA<4>(buf, 256, Bs, rl0, c0, kb, kB, acc);
    __builtin_amdgcn_s_setprio(0);
    __syncthreads();
  }
  {
    float bb0[4], bb1[4], bb2[4], bb3[4];
    int imv[4];
#pragma unroll
    for (int fn = 0; fn < 4; fn++){
      int col = colBase + fn*16 + (lane & 15);
      bb0[fn] = eb2[col]; bb1[fn] = eb2[256 + col];
      bb2[fn] = eb2[512 + col]; bb3[fn] = eb2[768 + col];
      imv[fn] = colmap[col];
    }
#pragma unroll
    for (int fm = 0; fm < 2; fm++)
#pragma unroll
      for (int i = 0; i < 4; i++){
        int rl = rowg*32 + fm*16 + (lane >> 4)*4 + i;
        int gr = rowBlk + rl;
        f32x4 dl = *(const f32x4*)&delta[gr*4];
        float d0a = fabsf(dl[0]), d1a = fabsf(dl[1]), d2a = fabsf(dl[2]), d3a = fabsf(dl[3]);
        int sw = (rl & 7) << 3;
#pragma unroll
        for (int fn = 0; fn < 4; fn++){
          int col = colBase + fn*16 + (lane & 15);
          float eff = acc[fm][fn][i] + d0a*bb0[fn] + d1a*bb1[fn] + d2a*bb2[fn] + d3a*bb3[fn];
          size_t idx = (size_t)gr*VDIM + col;
          effOut[idx] = eff;
          float base = (imv[fn] >= 0) ? IV[gr*4 + imv[fn]] : b2f(xcap[fm][i][fn]);
          buf[(size_t)rl*256 + (col ^ sw)] = f2b(base + eff);
        }
      }
  }
  __syncthreads();

  // ---- stage 3: final = Ds@M -> outF ; Fin -> buf ; impact partials -> LDS
#pragma unroll
  for (int fm = 0; fm < 2; fm++)
#pragma unroll
    for (int fn = 0; fn < 4; fn++) acc[fm][fn] = (f32x4){0.f,0.f,0.f,0.f};
  for (int kc = 0; kc < 4; kc++){
    int kB = kc * 64;
    stage256(Mt, kB, w, lane, Bs);
    __syncthreads();
    __builtin_amdgcn_s_setprio(1);
    mm_lA<4>(buf, 256, Bs, rl0, c0, kb, kB, acc);
    __builtin_amdgcn_s_setprio(0);
    __syncthreads();
  }
  {
#pragma unroll
    for (int fm = 0; fm < 2; fm++)
#pragma unroll
      for (int i = 0; i < 4; i++){
        int rl = rowg*32 + fm*16 + (lane >> 4)*4 + i;
        int gr = rowBlk + rl;
        int sw = (rl & 7) << 3;
        float ss = 0.f;
#pragma unroll
        for (int fn = 0; fn < 4; fn++){
          int col = colBase + fn*16 + (lane & 15);
          size_t idx = (size_t)gr*VDIM + col;
          float fv = acc[fm][fn][i];
          outF[idx] = fv;
          buf[(size_t)rl*256 + (col ^ sw)] = f2b(fv);
          float d = fv - b2f(xcap[fm][i][fn]);
          ss += d * d;
        }
        ss += __shfl_xor(ss, 1, 64); ss += __shfl_xor(ss, 2, 64);
        ss += __shfl_xor(ss, 4, 64); ss += __shfl_xor(ss, 8, 64);
        if ((lane & 15) == 0) impLds[rl*4 + colg] = ss;
      }
  }
  __syncthreads();

  // ---- stage 4: P1 = relu(XB@W1ab^T + Fin@W1c^T + delta corr + b1) -> buf
  {
    f32x4 a4[2][2];
#pragma unroll
    for (int fm = 0; fm < 2; fm++)
#pragma unroll
      for (int fn = 0; fn < 2; fn++) a4[fm][fn] = (f32x4){0.f,0.f,0.f,0.f};
    int c4 = colg * 32 + (lane & 15);
    for (int kc = 0; kc < 4; kc++){
      int kB = kc * 64;
      stage128(W1ab, kB, w, lane, Bs);           // rows 0..127
      stage128(W1c,  kB, w, lane, Bs + 8192);    // rows 128..255 (panel-local swz)
      stage64xb(XB, rowBlk, kB, w, lane, xbs);
      __syncthreads();
      __builtin_amdgcn_s_setprio(1);
      mm_xA<2>(xbs, Bs, rl0, c4, kb, a4);
      mm_lA<2>(buf, 256, Bs + 8192, rl0, c4, kb, kB, a4);
      __builtin_amdgcn_s_setprio(0);
      __syncthreads();
    }
    float bv[2];
    f32x4 wb[2];
#pragma unroll
    for (int fn = 0; fn < 2; fn++){
      int col = colg*32 + fn*16 + (lane & 15);
      bv[fn] = pb1[col];
      wb[fn] = *(const f32x4*)&w1bcol[col*4];
    }
#pragma unroll
    for (int fm = 0; fm < 2; fm++)
#pragma unroll
      for (int i = 0; i < 4; i++){
        int rl = rowg*32 + fm*16 + (lane >> 4)*4 + i;
        int gr = rowBlk + rl;
        f32x4 dl = *(const f32x4*)&delta[gr*4];
        int sw = (rl & 7) << 3;
#pragma unroll
        for (int fn = 0; fn < 2; fn++){
          int col = colg*32 + fn*16 + (lane & 15);
          float p = a4[fm][fn][i] + bv[fn]
                  + dl[0]*wb[fn][0] + dl[1]*wb[fn][1] + dl[2]*wb[fn][2] + dl[3]*wb[fn][3];
          p = p > 0.f ? p : 0.f;
          buf[(size_t)rl*128 + (col ^ sw)] = f2b(p);
        }
      }
  }
  __syncthreads();

  // ---- stage 5: P2 = relu(P1@W2^T + b2); plaus; impact finish
  if (w < 4){
    int rl0b = w * 16 + (lane & 15);
    f32x4 a2[4];
#pragma unroll
    for (int fn = 0; fn < 4; fn++) a2[fn] = (f32x4){0.f,0.f,0.f,0.f};
    mm_l1<4, 128>(buf, 128, W2bf, 128, rl0b, (lane & 15), kb, a2);
    float b2v[4], w3v[4];
#pragma unroll
    for (int fn = 0; fn < 4; fn++){
      int col = fn*16 + (lane & 15);
      b2v[fn] = pb2[col]; w3v[fn] = W3[col];
    }
    float b3v = pb3[0];
#pragma unroll
    for (int i = 0; i < 4; i++){
      float s = 0.f;
#pragma unroll
      for (int fn = 0; fn < 4; fn++){
        float p2 = a2[fn][i] + b2v[fn];
        p2 = p2 > 0.f ? p2 : 0.f;
        s += p2 * w3v[fn];
      }
      s += __shfl_xor(s, 1, 64); s += __shfl_xor(s, 2, 64);
      s += __shfl_xor(s, 4, 64); s += __shfl_xor(s, 8, 64);
      if ((lane & 15) == 0){
        int gr = rowBlk + w*16 + (lane >> 4)*4 + i;
        plausOut[gr] = 1.f / (1.f + expf(-(s + b3v)));
      }
    }
  } else if (w == 4){
    f32x4 v = *(const f32x4*)&impLds[lane * 4];
    impOut[rowBlk + lane] = sqrtf(v[0] + v[1] + v[2] + v[3]);
  }
}

// ---- workspace layout (bytes) ----------------------------------------------
#define WS_XB     ((size_t)0)           // 16 MB
#define WS_DELTA  ((size_t)16777216)    // 512 KB
#define WS_SEG    ((size_t)17301504)    // 4 MB
#define WS_T2     ((size_t)21495808)    // 1 MB
#define WS_R      ((size_t)22544384)    // 256 KB
#define WS_MT     ((size_t)22806528)    // 128 KB
#define WS_BT1    ((size_t)22937600)    // 128 KB
#define WS_BT2    ((size_t)23068672)    // 128 KB
#define WS_W1AB   ((size_t)23199744)    // 64 KB
#define WS_W1C    ((size_t)23265280)    // 64 KB
#define WS_W2BF   ((size_t)23330816)    // 16 KB
#define WS_W1BCOL ((size_t)23347200)    // 2 KB
#define WS_COLMAP ((size_t)23349248)    // 1 KB

extern "C" void kernel_launch(void* const* d_in, const int* in_sizes, int n_in,
                              void* d_out, int out_size, void* d_ws, size_t ws_size,
                              hipStream_t stream)
{
  const float* X     = (const float*)d_in[0];
  const float* IV    = (const float*)d_in[1];
  const float* STR   = (const float*)d_in[2];
  const int*   IVARS = (const int*)d_in[3];
  const int*   CIDX  = (const int*)d_in[4];
  const int*   EIDX  = (const int*)d_in[5];
  const float* EW1   = (const float*)d_in[6];
  const float* EB1   = (const float*)d_in[7];
  const float* EW2   = (const float*)d_in[8];
  const float* EB2   = (const float*)d_in[9];
  const float* PW1   = (const float*)d_in[10];
  const float* PB1   = (const float*)d_in[11];
  const float* PW2   = (const float*)d_in[12];
  const float* PB2   = (const float*)d_in[13];
  const float* PW3   = (const float*)d_in[14];
  const float* PB3   = (const float*)d_in[15];

  char* ws = (char*)d_ws;
  unsigned short* XB     = (unsigned short*)(ws + WS_XB);
  float*          DELTA  = (float*)(ws + WS_DELTA);
  float*          SEG    = (float*)(ws + WS_SEG);
  float*          T2     = (float*)(ws + WS_T2);
  float*          Rm     = (float*)(ws + WS_R);
  unsigned short* MT     = (unsigned short*)(ws + WS_MT);
  unsigned short* BT1    = (unsigned short*)(ws + WS_BT1);
  unsigned short* BT2    = (unsigned short*)(ws + WS_BT2);
  unsigned short* W1AB   = (unsigned short*)(ws + WS_W1AB);
  unsigned short* W1C    = (unsigned short*)(ws + WS_W1C);
  unsigned short* W2BF   = (unsigned short*)(ws + WS_W2BF);
  float*          W1BCOL = (float*)(ws + WS_W1BCOL);
  int*            COLMAP = (int*)(ws + WS_COLMAP);

  float* outF   = (float*)d_out;                       // final_cf  [B,V]
  float* outEff = outF + (size_t)BDIM * VDIM;          // effects   [B,V]
  float* outPl  = outEff + (size_t)BDIM * VDIM;        // plaus     [B]
  float* outIm  = outPl + BDIM;                        // impact    [B]

  prep_seg<<<2048, 256, 0, stream>>>(X, IV, IVARS, EW1, EW2, PW1, PW2,
                                     CIDX, EIDX, STR,
                                     XB, BT1, BT2, W1AB, W1C, W2BF, W1BCOL, COLMAP,
                                     DELTA, SEG);
  combine4<<<256, 256, 0, stream>>>(SEG, T2);    // 16 segs -> 4
  combine4<<<64, 256, 0, stream>>>(T2, Rm);      // 4 -> R
  powM<<<64, 256, 0, stream>>>(Rm, MT);          // M = R^3, transposed bf16

  mega<<<512, 512, 0, stream>>>(IV, XB, BT1, BT2, MT, W1AB, W1C, W2BF,
                                EB1, EB2, DELTA, COLMAP, W1BCOL,
                                PB1, PB2, PW3, PB3,
                                outEff, outF, outPl, outIm);

  (void)in_sizes; (void)n_in; (void)out_size; (void)ws_size;
}

// Round 4
// 193.287 us; speedup vs baseline: 1.2942x; 1.0009x over previous
//
#include <hip/hip_runtime.h>

#define BDIM 32768
#define VDIM 256
#define KVAR 4
#define EDIM 2048
#define SEGS 16
#define SEGLEN 128   // EDIM / SEGS

typedef __attribute__((ext_vector_type(8))) short short8;
typedef __attribute__((ext_vector_type(4))) float f32x4;

__device__ __forceinline__ unsigned short f2b(float f){
  union { float f; unsigned u; } v; v.f = f;
  unsigned r = v.u + 0x7FFFu + ((v.u >> 16) & 1u);   // round-to-nearest-even
  return (unsigned short)(r >> 16);
}
__device__ __forceinline__ float b2f(unsigned short h){
  union { unsigned u; float f; } v; v.u = ((unsigned)h) << 16;
  return v.f;
}
__device__ __forceinline__ short8 ldb8(const unsigned short* p){
  return *(const short8*)p;
}

// async 16B global -> LDS (dest = wave-uniform base + lane*16)
__device__ __forceinline__ void gl_lds16(const unsigned short* g, unsigned short* l){
  __builtin_amdgcn_global_load_lds(
      (const __attribute__((address_space(1))) unsigned int*)g,
      (__attribute__((address_space(3))) unsigned int*)l, 16, 0, 0);
}

// ---- LDS staging -----------------------------------------------------------
// Panel layout: row r -> 64 k-elems (128 B = 8 slots of 16B); LDS slot s holds
// global slot (s ^ (r&7))  [source-swizzled so swizzled reads are conflict-free]
// One wave issue = 8 rows (64 lanes x 16B = 1 KB).
__device__ __forceinline__ void stage256(const unsigned short* Bt, int kB,
                                         int w, int lane, unsigned short* Bs){
#pragma unroll
  for (int i = 0; i < 4; i++){
    int g8 = i*8 + w;                  // row-group of 8 (0..31)
    int r  = g8*8 + (lane >> 3);
    int s  = lane & 7;
    gl_lds16(Bt + (size_t)r*VDIM + kB + ((s ^ (r & 7)) << 3),
             Bs + (size_t)g8*512);
  }
}
__device__ __forceinline__ void stage128(const unsigned short* Bt, int kB,
                                         int w, int lane, unsigned short* Bs){
#pragma unroll
  for (int i = 0; i < 2; i++){
    int g8 = i*8 + w;                  // 0..15
    int r  = g8*8 + (lane >> 3);       // 0..127
    int s  = lane & 7;
    gl_lds16(Bt + (size_t)r*VDIM + kB + ((s ^ (r & 7)) << 3),
             Bs + (size_t)g8*512);
  }
}
// XB stripe k-chunk: 64 rows x 64 k -> 8 KB, one DMA per wave
__device__ __forceinline__ void stage64xb(const unsigned short* XBg, int rowBlk, int kB,
                                          int w, int lane, unsigned short* xbs){
  int r = w*8 + (lane >> 3);           // 0..63
  int s = lane & 7;
  gl_lds16(XBg + (size_t)(rowBlk + r)*VDIM + kB + ((s ^ (r & 7)) << 3),
           xbs + (size_t)w*512);
}

// swizzled fragment read (klocal = k within 64-chunk, multiple of 8)
__device__ __forceinline__ short8 bs_frag(const unsigned short* Bs, int c, int klocal){
  int slot = klocal >> 3;
  return *(const short8*)&Bs[(size_t)c*64 + ((slot ^ (c & 7)) << 3)];
}

// ---- MFMA chunk cores (one 64-wide K-chunk) --------------------------------
// D frag: col = lane&15, row = (lane>>4)*4 + reg   [measured: learn_hip m89]
// A from xbs (64-elem swizzled rows), B from swizzled Bs.
template<int NF>
__device__ __forceinline__ void mm_xA(const unsigned short* xbs, const unsigned short* Bs,
                                      int rl0, int c0, int kb, f32x4 (&acc)[2][NF])
{
  int sw = (rl0 & 7) << 3;             // (rl0+16)&7 == rl0&7
#pragma unroll
  for (int k = 0; k < 2; k++){
    int kl = k*32 + kb;
    short8 a0 = *(const short8*)&xbs[(size_t)rl0*64 + (kl ^ sw)];
    short8 a1 = *(const short8*)&xbs[(size_t)(rl0+16)*64 + (kl ^ sw)];
#pragma unroll
    for (int fn = 0; fn < NF; fn++){
      short8 b = bs_frag(Bs, c0 + fn*16, kl);
      acc[0][fn] = __builtin_amdgcn_mfma_f32_16x16x32_bf16(a0, b, acc[0][fn], 0, 0, 0);
      acc[1][fn] = __builtin_amdgcn_mfma_f32_16x16x32_bf16(a1, b, acc[1][fn], 0, 0, 0);
    }
  }
}
// A from XOR-swizzled LDS buf (element col ^ ((row&7)<<3), 256-elem rows)
template<int NF>
__device__ __forceinline__ void mm_lA(const unsigned short* Alds, int ldaE,
                                      const unsigned short* Bs,
                                      int rl0, int c0, int kb, int kB,
                                      f32x4 (&acc)[2][NF])
{
  int sw = (rl0 & 7) << 3;
#pragma unroll
  for (int k = 0; k < 2; k++){
    int ka = kB + k*32 + kb;
    short8 a0 = *(const short8*)&Alds[(size_t)rl0 * ldaE + (ka ^ sw)];
    short8 a1 = *(const short8*)&Alds[(size_t)(rl0+16) * ldaE + (ka ^ sw)];
#pragma unroll
    for (int fn = 0; fn < NF; fn++){
      short8 b = bs_frag(Bs, c0 + fn*16, k*32 + kb);
      acc[0][fn] = __builtin_amdgcn_mfma_f32_16x16x32_bf16(a0, b, acc[0][fn], 0, 0, 0);
      acc[1][fn] = __builtin_amdgcn_mfma_f32_16x16x32_bf16(a1, b, acc[1][fn], 0, 0, 0);
    }
  }
}
// single 16-row A frag, B from global (tiny W2 panel, stage-5 only)
template<int NF, int KSZ>
__device__ __forceinline__ void mm_l1(const unsigned short* Alds, int ldaE,
                                      const unsigned short* Bt, int ldb,
                                      int rl0, int c0, int kb,
                                      f32x4 (&acc)[NF])
{
  int sw = (rl0 & 7) << 3;
#pragma unroll
  for (int k0 = 0; k0 < KSZ; k0 += 32){
    int ka = k0 + kb;
    short8 a0 = *(const short8*)&Alds[(size_t)rl0 * ldaE + (ka ^ sw)];
#pragma unroll
    for (int fn = 0; fn < NF; fn++){
      short8 b = ldb8(Bt + (size_t)(c0 + fn*16)*ldb + ka);
      acc[fn] = __builtin_amdgcn_mfma_f32_16x16x32_bf16(a0, b, acc[fn], 0, 0, 0);
    }
  }
}

// ---- merged prep + seg_build (block-partitioned) ---------------------------
__global__ __launch_bounds__(256) void prep_seg(
    const float* X, const float* IV, const int* ivars,
    const float* eW1, const float* eW2, const float* pW1, const float* pW2,
    const int* cidx, const int* eidx, const float* stren,
    unsigned short* XB,
    unsigned short* bt1, unsigned short* bt2,
    unsigned short* w1ab, unsigned short* w1c,
    unsigned short* w2bf, float* w1bcol, int* colmap,
    float* delta, float* segs)
{
  if (blockIdx.x < 1024){
    __shared__ int lc[SEGLEN];
    __shared__ int le[SEGLEN];
    __shared__ float la[SEGLEN];
    int bid = blockIdx.x;            // 64 per segment, 4 rows each
    int seg = bid >> 6;
    int rowbase = (bid & 63) * 4;
    int w = threadIdx.x >> 6, lane = threadIdx.x & 63;
    int row = rowbase + w;
    int k0 = seg * SEGLEN;
    for (int t = threadIdx.x; t < SEGLEN; t += 256){
      lc[t] = cidx[k0 + t]; le[t] = eidx[k0 + t]; la[t] = stren[k0 + t] * 0.1f;
    }
    __syncthreads();
    float r0 = (row == lane)        ? 1.f : 0.f;
    float r1 = (row == lane + 64)   ? 1.f : 0.f;
    float r2 = (row == lane + 128)  ? 1.f : 0.f;
    float r3 = (row == lane + 192)  ? 1.f : 0.f;
    for (int t = 0; t < SEGLEN; t++){
      int cs = __builtin_amdgcn_readfirstlane(lc[t]);
      int es = __builtin_amdgcn_readfirstlane(le[t]);
      float a = la[t];
      float vr;
      switch (cs >> 6){ case 0: vr = r0; break; case 1: vr = r1; break;
                        case 2: vr = r2; break; default: vr = r3; }
      float v = __shfl(vr, cs & 63, 64);
      float add = (lane == (es & 63)) ? a * v : 0.f;
      switch (es >> 6){ case 0: r0 += add; break; case 1: r1 += add; break;
                        case 2: r2 += add; break; default: r3 += add; }
    }
    float* out = segs + (size_t)seg * 65536 + (size_t)row * 256;
    out[lane] = r0; out[lane + 64] = r1; out[lane + 128] = r2; out[lane + 192] = r3;
    return;
  }
  int stride = 1024 * 256;
  int g0 = (blockIdx.x - 1024) * 256 + threadIdx.x;
  for (int i = g0; i < (BDIM * VDIM) / 8; i += stride){
    const float* p = X + (size_t)i * 8;
    f32x4 lo = *(const f32x4*)p;
    f32x4 hi = *(const f32x4*)(p + 4);
    short8 r;
    r[0]=(short)f2b(lo[0]); r[1]=(short)f2b(lo[1]); r[2]=(short)f2b(lo[2]); r[3]=(short)f2b(lo[3]);
    r[4]=(short)f2b(hi[0]); r[5]=(short)f2b(hi[1]); r[6]=(short)f2b(hi[2]); r[7]=(short)f2b(hi[3]);
    *(short8*)(XB + (size_t)i * 8) = r;
  }
  for (int i = g0; i < 65536; i += stride) bt1[i] = f2b(eW1[i]);
  for (int i = g0; i < 65536; i += stride){
    int v = i >> 8, r = i & 255;
    bt2[i] = f2b(eW2[(r >> 6) * 16384 + v * 64 + (r & 63)]);
  }
  for (int i = g0; i < 32768; i += stride){
    int o = i >> 8, v = i & 255;
    w1ab[i] = f2b(pW1[o*768 + v] + pW1[o*768 + 256 + v]);
    w1c[i]  = f2b(pW1[o*768 + 512 + v]);
  }
  for (int i = g0; i < 8192; i += stride) w2bf[i] = f2b(pW2[i]);
  for (int i = g0; i < 512; i += stride){
    int o = i >> 2, k = i & 3;
    w1bcol[i] = pW1[o*768 + 256 + ivars[k]];
  }
  for (int i = g0; i < VDIM; i += stride){
    int m = -1;
#pragma unroll
    for (int k = 0; k < KVAR; k++) if (ivars[k] == i) m = k;
    colmap[i] = m;
  }
  for (int i = g0; i < BDIM * KVAR; i += stride){
    int b = i >> 2, k = i & 3;
    delta[i] = IV[i] - X[(size_t)b * VDIM + ivars[k]];
  }
}

// ---- combine: Out[m] = S[4m]*S[4m+1]*S[4m+2]*S[4m+3], 4 rows per block -----
__global__ __launch_bounds__(256) void combine4(const float* S, float* Out)
{
  int m = blockIdx.x >> 6;
  int rb = (blockIdx.x & 63) * 4;
  int c = threadIdx.x;
  __shared__ float v[4][256];
  const float* base = S + (size_t)m * 4 * 65536;
#pragma unroll
  for (int r = 0; r < 4; r++) v[r][c] = base[(size_t)(rb + r) * 256 + c];
  __syncthreads();
  for (int p = 1; p < 4; p++){
    const float* Bm = base + (size_t)p * 65536;
    float a0 = 0.f, a1 = 0.f, a2 = 0.f, a3 = 0.f;
    for (int k = 0; k < 256; k += 4){
      f32x4 v0 = *(const f32x4*)&v[0][k];
      f32x4 v1 = *(const f32x4*)&v[1][k];
      f32x4 v2 = *(const f32x4*)&v[2][k];
      f32x4 v3 = *(const f32x4*)&v[3][k];
#pragma unroll
      for (int j = 0; j < 4; j++){
        float bk = Bm[(size_t)(k + j) * 256 + c];
        a0 += v0[j] * bk; a1 += v1[j] * bk; a2 += v2[j] * bk; a3 += v3[j] * bk;
      }
    }
    __syncthreads();
    v[0][c] = a0; v[1][c] = a1; v[2][c] = a2; v[3][c] = a3;
    __syncthreads();
  }
#pragma unroll
  for (int r = 0; r < 4; r++) Out[(size_t)m * 65536 + (size_t)(rb + r) * 256 + c] = v[r][c];
}

// ---- M = R*R*R, written transposed bf16: Mt[c][r] --------------------------
__global__ __launch_bounds__(256) void powM(const float* R, unsigned short* Mt)
{
  int rb = blockIdx.x * 4;
  int c = threadIdx.x;
  __shared__ float v[4][256];
#pragma unroll
  for (int r = 0; r < 4; r++) v[r][c] = R[(size_t)(rb + r) * 256 + c];
  __syncthreads();
  for (int p = 0; p < 2; p++){
    float a0 = 0.f, a1 = 0.f, a2 = 0.f, a3 = 0.f;
    for (int k = 0; k < 256; k += 4){
      f32x4 v0 = *(const f32x4*)&v[0][k];
      f32x4 v1 = *(const f32x4*)&v[1][k];
      f32x4 v2 = *(const f32x4*)&v[2][k];
      f32x4 v3 = *(const f32x4*)&v[3][k];
#pragma unroll
      for (int j = 0; j < 4; j++){
        float bk = R[(size_t)(k + j) * 256 + c];
        a0 += v0[j] * bk; a1 += v1[j] * bk; a2 += v2[j] * bk; a3 += v3[j] * bk;
      }
    }
    __syncthreads();
    v[0][c] = a0; v[1][c] = a1; v[2][c] = a2; v[3][c] = a3;
    __syncthreads();
  }
#pragma unroll
  for (int r = 0; r < 4; r++) Mt[(size_t)c * 256 + (rb + r)] = f2b(v[r][c]);
}

// ---- MEGA: H -> eff -> final -> P1 -> P2/plaus + impact --------------------
// 64-row stripe per block, 8 waves (2 rowg x 4 colg), wave tile 32x64.
// waves_per_eu(4,4): LDS (73KB) caps at 2 blocks/CU = 4 waves/EU anyway, so
// pin the allocator to the 128-VGPR budget. Without the pin the backend
// squeezed to 64 VGPRs (8-wave bucket) and spilled ~100 dwords/thread
// (rocprof: WRITE_SIZE 170MB vs 64 ideal, +404 B/thread -- scratch traffic;
// spill-reload latency chains explain the 90% all-pipes-idle stall).
__global__ __launch_bounds__(512) __attribute__((amdgpu_waves_per_eu(4, 4))) void mega(
    const float* IV, const unsigned short* XB,
    const unsigned short* Bt1, const unsigned short* Bt2, const unsigned short* Mt,
    const unsigned short* W1ab, const unsigned short* W1c, const unsigned short* W2bf,
    const float* eb1, const float* eb2, const float* delta, const int* colmap,
    const float* w1bcol, const float* pb1, const float* pb2,
    const float* W3, const float* pb3,
    float* effOut, float* outF, float* plausOut, float* impOut)
{
  __shared__ unsigned short buf[64 * 256];   // 32 KB, stage-to-stage scratch
  __shared__ unsigned short Bs[256 * 64];    // 32 KB, B-panel K-chunk
  __shared__ unsigned short xbs[64 * 64];    // 8 KB, XB stripe K-chunk
  __shared__ float impLds[64 * 4];
  int tid = threadIdx.x, w = tid >> 6, lane = tid & 63;
  int rowg = w >> 2, colg = w & 3;
  int rowBlk = blockIdx.x * 64;
  int rl0 = rowg * 32 + (lane & 15);
  int colBase = colg * 64;
  int c0 = colBase + (lane & 15);
  int kb = (lane >> 4) * 8;
  f32x4 acc[2][4];
  unsigned short xcap[2][4][4];              // XB at this thread's D positions

  // ---- stage 1: H = relu(XB@W1^T + b1) * |delta_k| -> buf (swizzled bf16)
#pragma unroll
  for (int fm = 0; fm < 2; fm++)
#pragma unroll
    for (int fn = 0; fn < 4; fn++) acc[fm][fn] = (f32x4){0.f,0.f,0.f,0.f};
  for (int kc = 0; kc < 4; kc++){
    int kB = kc * 64;
    stage256(Bt1, kB, w, lane, Bs);
    stage64xb(XB, rowBlk, kB, w, lane, xbs);
    __syncthreads();
    __builtin_amdgcn_s_setprio(1);
    mm_xA<4>(xbs, Bs, rl0, c0, kb, acc);
    __builtin_amdgcn_s_setprio(0);
    if (colg == kc){                         // capture XB at D positions
#pragma unroll
      for (int fm = 0; fm < 2; fm++)
#pragma unroll
        for (int i = 0; i < 4; i++){
          int rl = rowg*32 + fm*16 + (lane >> 4)*4 + i;
          int sw = (rl & 7) << 3;
#pragma unroll
          for (int fn = 0; fn < 4; fn++){
            int lc = fn*16 + (lane & 15);
            xcap[fm][i][fn] = xbs[(size_t)rl*64 + (lc ^ sw)];
          }
        }
    }
    __syncthreads();
  }
  {
    float b1v[4];
#pragma unroll
    for (int fn = 0; fn < 4; fn++) b1v[fn] = eb1[colBase + fn*16 + (lane & 15)];
#pragma unroll
    for (int fm = 0; fm < 2; fm++)
#pragma unroll
      for (int i = 0; i < 4; i++){
        int rl = rowg*32 + fm*16 + (lane >> 4)*4 + i;
        int gr = rowBlk + rl;
        float mg = fabsf(delta[gr*4 + colg]);
        int sw = (rl & 7) << 3;
#pragma unroll
        for (int fn = 0; fn < 4; fn++){
          int col = colBase + fn*16 + (lane & 15);
          float h = acc[fm][fn][i] + b1v[fn];
          h = h > 0.f ? h : 0.f;
          buf[(size_t)rl*256 + (col ^ sw)] = f2b(h * mg);
        }
      }
  }
  __syncthreads();

  // ---- stage 2: eff = Hs@W2f + sum|d_k| b2[k] ; d0 -> buf
#pragma unroll
  for (int fm = 0; fm < 2; fm++)
#pragma unroll
    for (int fn = 0; fn < 4; fn++) acc[fm][fn] = (f32x4){0.f,0.f,0.f,0.f};
  for (int kc = 0; kc < 4; kc++){
    int kB = kc * 64;
    stage256(Bt2, kB, w, lane, Bs);
    __syncthreads();
    __builtin_amdgcn_s_setprio(1);
    mm_lA<4>(buf, 256, Bs, rl0, c0, kb, kB, acc);
    __builtin_amdgcn_s_setprio(0);
    __syncthreads();
  }
  {
    float bb0[4], bb1[4], bb2[4], bb3[4];
    int imv[4];
#pragma unroll
    for (int fn = 0; fn < 4; fn++){
      int col = colBase + fn*16 + (lane & 15);
      bb0[fn] = eb2[col]; bb1[fn] = eb2[256 + col];
      bb2[fn] = eb2[512 + col]; bb3[fn] = eb2[768 + col];
      imv[fn] = colmap[col];
    }
#pragma unroll
    for (int fm = 0; fm < 2; fm++)
#pragma unroll
      for (int i = 0; i < 4; i++){
        int rl = rowg*32 + fm*16 + (lane >> 4)*4 + i;
        int gr = rowBlk + rl;
        f32x4 dl = *(const f32x4*)&delta[gr*4];
        float d0a = fabsf(dl[0]), d1a = fabsf(dl[1]), d2a = fabsf(dl[2]), d3a = fabsf(dl[3]);
        int sw = (rl & 7) << 3;
#pragma unroll
        for (int fn = 0; fn < 4; fn++){
          int col = colBase + fn*16 + (lane & 15);
          float eff = acc[fm][fn][i] + d0a*bb0[fn] + d1a*bb1[fn] + d2a*bb2[fn] + d3a*bb3[fn];
          size_t idx = (size_t)gr*VDIM + col;
          effOut[idx] = eff;
          float base = (imv[fn] >= 0) ? IV[gr*4 + imv[fn]] : b2f(xcap[fm][i][fn]);
          buf[(size_t)rl*256 + (col ^ sw)] = f2b(base + eff);
        }
      }
  }
  __syncthreads();

  // ---- stage 3: final = Ds@M -> outF ; Fin -> buf ; impact partials -> LDS
#pragma unroll
  for (int fm = 0; fm < 2; fm++)
#pragma unroll
    for (int fn = 0; fn < 4; fn++) acc[fm][fn] = (f32x4){0.f,0.f,0.f,0.f};
  for (int kc = 0; kc < 4; kc++){
    int kB = kc * 64;
    stage256(Mt, kB, w, lane, Bs);
    __syncthreads();
    __builtin_amdgcn_s_setprio(1);
    mm_lA<4>(buf, 256, Bs, rl0, c0, kb, kB, acc);
    __builtin_amdgcn_s_setprio(0);
    __syncthreads();
  }
  {
#pragma unroll
    for (int fm = 0; fm < 2; fm++)
#pragma unroll
      for (int i = 0; i < 4; i++){
        int rl = rowg*32 + fm*16 + (lane >> 4)*4 + i;
        int gr = rowBlk + rl;
        int sw = (rl & 7) << 3;
        float ss = 0.f;
#pragma unroll
        for (int fn = 0; fn < 4; fn++){
          int col = colBase + fn*16 + (lane & 15);
          size_t idx = (size_t)gr*VDIM + col;
          float fv = acc[fm][fn][i];
          outF[idx] = fv;
          buf[(size_t)rl*256 + (col ^ sw)] = f2b(fv);
          float d = fv - b2f(xcap[fm][i][fn]);
          ss += d * d;
        }
        ss += __shfl_xor(ss, 1, 64); ss += __shfl_xor(ss, 2, 64);
        ss += __shfl_xor(ss, 4, 64); ss += __shfl_xor(ss, 8, 64);
        if ((lane & 15) == 0) impLds[rl*4 + colg] = ss;
      }
  }
  __syncthreads();

  // ---- stage 4: P1 = relu(XB@W1ab^T + Fin@W1c^T + delta corr + b1) -> buf
  {
    f32x4 a4[2][2];
#pragma unroll
    for (int fm = 0; fm < 2; fm++)
#pragma unroll
      for (int fn = 0; fn < 2; fn++) a4[fm][fn] = (f32x4){0.f,0.f,0.f,0.f};
    int c4 = colg * 32 + (lane & 15);
    for (int kc = 0; kc < 4; kc++){
      int kB = kc * 64;
      stage128(W1ab, kB, w, lane, Bs);           // rows 0..127
      stage128(W1c,  kB, w, lane, Bs + 8192);    // rows 128..255 (panel-local swz)
      stage64xb(XB, rowBlk, kB, w, lane, xbs);
      __syncthreads();
      __builtin_amdgcn_s_setprio(1);
      mm_xA<2>(xbs, Bs, rl0, c4, kb, a4);
      mm_lA<2>(buf, 256, Bs + 8192, rl0, c4, kb, kB, a4);
      __builtin_amdgcn_s_setprio(0);
      __syncthreads();
    }
    float bv[2];
    f32x4 wb[2];
#pragma unroll
    for (int fn = 0; fn < 2; fn++){
      int col = colg*32 + fn*16 + (lane & 15);
      bv[fn] = pb1[col];
      wb[fn] = *(const f32x4*)&w1bcol[col*4];
    }
#pragma unroll
    for (int fm = 0; fm < 2; fm++)
#pragma unroll
      for (int i = 0; i < 4; i++){
        int rl = rowg*32 + fm*16 + (lane >> 4)*4 + i;
        int gr = rowBlk + rl;
        f32x4 dl = *(const f32x4*)&delta[gr*4];
        int sw = (rl & 7) << 3;
#pragma unroll
        for (int fn = 0; fn < 2; fn++){
          int col = colg*32 + fn*16 + (lane & 15);
          float p = a4[fm][fn][i] + bv[fn]
                  + dl[0]*wb[fn][0] + dl[1]*wb[fn][1] + dl[2]*wb[fn][2] + dl[3]*wb[fn][3];
          p = p > 0.f ? p : 0.f;
          buf[(size_t)rl*128 + (col ^ sw)] = f2b(p);
        }
      }
  }
  __syncthreads();

  // ---- stage 5: P2 = relu(P1@W2^T + b2); plaus; impact finish
  if (w < 4){
    int rl0b = w * 16 + (lane & 15);
    f32x4 a2[4];
#pragma unroll
    for (int fn = 0; fn < 4; fn++) a2[fn] = (f32x4){0.f,0.f,0.f,0.f};
    mm_l1<4, 128>(buf, 128, W2bf, 128, rl0b, (lane & 15), kb, a2);
    float b2v[4], w3v[4];
#pragma unroll
    for (int fn = 0; fn < 4; fn++){
      int col = fn*16 + (lane & 15);
      b2v[fn] = pb2[col]; w3v[fn] = W3[col];
    }
    float b3v = pb3[0];
#pragma unroll
    for (int i = 0; i < 4; i++){
      float s = 0.f;
#pragma unroll
      for (int fn = 0; fn < 4; fn++){
        float p2 = a2[fn][i] + b2v[fn];
        p2 = p2 > 0.f ? p2 : 0.f;
        s += p2 * w3v[fn];
      }
      s += __shfl_xor(s, 1, 64); s += __shfl_xor(s, 2, 64);
      s += __shfl_xor(s, 4, 64); s += __shfl_xor(s, 8, 64);
      if ((lane & 15) == 0){
        int gr = rowBlk + w*16 + (lane >> 4)*4 + i;
        plausOut[gr] = 1.f / (1.f + expf(-(s + b3v)));
      }
    }
  } else if (w == 4){
    f32x4 v = *(const f32x4*)&impLds[lane * 4];
    impOut[rowBlk + lane] = sqrtf(v[0] + v[1] + v[2] + v[3]);
  }
}

// ---- workspace layout (bytes) ----------------------------------------------
#define WS_XB     ((size_t)0)           // 16 MB
#define WS_DELTA  ((size_t)16777216)    // 512 KB
#define WS_SEG    ((size_t)17301504)    // 4 MB
#define WS_T2     ((size_t)21495808)    // 1 MB
#define WS_R      ((size_t)22544384)    // 256 KB
#define WS_MT     ((size_t)22806528)    // 128 KB
#define WS_BT1    ((size_t)22937600)    // 128 KB
#define WS_BT2    ((size_t)23068672)    // 128 KB
#define WS_W1AB   ((size_t)23199744)    // 64 KB
#define WS_W1C    ((size_t)23265280)    // 64 KB
#define WS_W2BF   ((size_t)23330816)    // 16 KB
#define WS_W1BCOL ((size_t)23347200)    // 2 KB
#define WS_COLMAP ((size_t)23349248)    // 1 KB

extern "C" void kernel_launch(void* const* d_in, const int* in_sizes, int n_in,
                              void* d_out, int out_size, void* d_ws, size_t ws_size,
                              hipStream_t stream)
{
  const float* X     = (const float*)d_in[0];
  const float* IV    = (const float*)d_in[1];
  const float* STR   = (const float*)d_in[2];
  const int*   IVARS = (const int*)d_in[3];
  const int*   CIDX  = (const int*)d_in[4];
  const int*   EIDX  = (const int*)d_in[5];
  const float* EW1   = (const float*)d_in[6];
  const float* EB1   = (const float*)d_in[7];
  const float* EW2   = (const float*)d_in[8];
  const float* EB2   = (const float*)d_in[9];
  const float* PW1   = (const float*)d_in[10];
  const float* PB1   = (const float*)d_in[11];
  const float* PW2   = (const float*)d_in[12];
  const float* PB2   = (const float*)d_in[13];
  const float* PW3   = (const float*)d_in[14];
  const float* PB3   = (const float*)d_in[15];

  char* ws = (char*)d_ws;
  unsigned short* XB     = (unsigned short*)(ws + WS_XB);
  float*          DELTA  = (float*)(ws + WS_DELTA);
  float*          SEG    = (float*)(ws + WS_SEG);
  float*          T2     = (float*)(ws + WS_T2);
  float*          Rm     = (float*)(ws + WS_R);
  unsigned short* MT     = (unsigned short*)(ws + WS_MT);
  unsigned short* BT1    = (unsigned short*)(ws + WS_BT1);
  unsigned short* BT2    = (unsigned short*)(ws + WS_BT2);
  unsigned short* W1AB   = (unsigned short*)(ws + WS_W1AB);
  unsigned short* W1C    = (unsigned short*)(ws + WS_W1C);
  unsigned short* W2BF   = (unsigned short*)(ws + WS_W2BF);
  float*          W1BCOL = (float*)(ws + WS_W1BCOL);
  int*            COLMAP = (int*)(ws + WS_COLMAP);

  float* outF   = (float*)d_out;                       // final_cf  [B,V]
  float* outEff = outF + (size_t)BDIM * VDIM;          // effects   [B,V]
  float* outPl  = outEff + (size_t)BDIM * VDIM;        // plaus     [B]
  float* outIm  = outPl + BDIM;                        // impact    [B]

  prep_seg<<<2048, 256, 0, stream>>>(X, IV, IVARS, EW1, EW2, PW1, PW2,
                                     CIDX, EIDX, STR,
                                     XB, BT1, BT2, W1AB, W1C, W2BF, W1BCOL, COLMAP,
                                     DELTA, SEG);
  combine4<<<256, 256, 0, stream>>>(SEG, T2);    // 16 segs -> 4
  combine4<<<64, 256, 0, stream>>>(T2, Rm);      // 4 -> R
  powM<<<64, 256, 0, stream>>>(Rm, MT);          // M = R^3, transposed bf16

  mega<<<512, 512, 0, stream>>>(IV, XB, BT1, BT2, MT, W1AB, W1C, W2BF,
                                EB1, EB2, DELTA, COLMAP, W1BCOL,
                                PB1, PB2, PW3, PB3,
                                outEff, outF, outPl, outIm);

  (void)in_sizes; (void)n_in; (void)out_size; (void)ws_size;
}